// Round 1
// baseline (3036.090 us; speedup 1.0000x reference)
//
#include <hip/hip_runtime.h>
#include <hip/hip_bf16.h>
#include <math.h>

#define NNODES 50000
#define NEDGES 500000
#define NTOT   (NEDGES + NNODES)   // 550000 edges incl. self-loops
#define D1     512
#define NH     4
#define NC     128
#define LN_EPS 1e-5f
#define NEG_SLOPE 0.2f

// ---------------- CSR build (counting sort by dst) ----------------

__global__ void k_count(const int* __restrict__ ei, int* __restrict__ counts) {
    int e = blockIdx.x * blockDim.x + threadIdx.x;
    if (e >= NTOT) return;
    int d = (e < NEDGES) ? ei[NEDGES + e] : (e - NEDGES);
    atomicAdd(&counts[d], 1);
}

__global__ void k_scan(const int* __restrict__ counts, int* __restrict__ offs) {
    __shared__ int s[1024];
    int tid = threadIdx.x;
    int running = 0;
    for (int i0 = 0; i0 < NNODES; i0 += 1024) {
        int idx = i0 + tid;
        int v = (idx < NNODES) ? counts[idx] : 0;
        s[tid] = v;
        __syncthreads();
        for (int d = 1; d < 1024; d <<= 1) {
            int t = (tid >= d) ? s[tid - d] : 0;
            __syncthreads();
            s[tid] += t;
            __syncthreads();
        }
        if (idx < NNODES) offs[idx] = running + s[tid] - v;  // exclusive
        int tot = s[1023];
        __syncthreads();
        running += tot;
    }
    if (tid == 0) offs[NNODES] = running;
}

__global__ void k_fill(const int* __restrict__ ei, int* __restrict__ cursor,
                       int* __restrict__ srcs) {
    int e = blockIdx.x * blockDim.x + threadIdx.x;
    if (e >= NTOT) return;
    int s, d;
    if (e < NEDGES) { s = ei[e]; d = ei[NEDGES + e]; }
    else            { s = d = e - NEDGES; }
    int pos = atomicAdd(&cursor[d], 1);
    srcs[pos] = s;
}

// ---------------- attention logits: als/ald [N,H] ----------------

__global__ void k_attn_logits(const float* __restrict__ h, const float* __restrict__ a_s,
                              const float* __restrict__ a_d, float* __restrict__ als,
                              float* __restrict__ ald) {
    int n = blockIdx.x, tid = threadIdx.x;  // 512 threads
    __shared__ float r1[512], r2[512];
    float hv = h[(size_t)n * D1 + tid];
    r1[tid] = hv * a_s[tid];
    r2[tid] = hv * a_d[tid];
    __syncthreads();
    for (int s = 64; s >= 1; s >>= 1) {
        if ((tid & 127) < s) { r1[tid] += r1[tid + s]; r2[tid] += r2[tid + s]; }
        __syncthreads();
    }
    if ((tid & 127) == 0) {
        als[n * NH + (tid >> 7)] = r1[tid];
        ald[n * NH + (tid >> 7)] = r2[tid];
    }
}

// ------------- GAT aggregation + bias + LayerNorm + ELU -------------

__global__ void k_gat_aggregate(const float* __restrict__ h, const float* __restrict__ als,
                                const float* __restrict__ ald, const int* __restrict__ offs,
                                const int* __restrict__ srcs, const float* __restrict__ bias,
                                const float* __restrict__ gamma, const float* __restrict__ beta,
                                float* __restrict__ out) {
    int n = blockIdx.x, tid = threadIdx.x;  // 512 threads, one block per node
    int e0 = offs[n], e1 = offs[n + 1];
    __shared__ float s_m[NH], s_d[NH];
    __shared__ float s_alpha[32 * NH];
    __shared__ float rbuf[512];

    if (tid < NH) {  // per-head softmax stats over this node's in-edges
        float ad = ald[n * NH + tid];
        float m = -1e30f;
        for (int k = e0; k < e1; k++) {
            float e = als[srcs[k] * NH + tid] + ad;
            e = (e >= 0.f) ? e : NEG_SLOPE * e;
            m = fmaxf(m, e);
        }
        float sum = 0.f;
        for (int k = e0; k < e1; k++) {
            float e = als[srcs[k] * NH + tid] + ad;
            e = (e >= 0.f) ? e : NEG_SLOPE * e;
            sum += __expf(e - m);
        }
        s_m[tid] = m; s_d[tid] = sum;
    }
    __syncthreads();

    float acc = 0.f;
    int head = tid >> 7;
    for (int base = e0; base < e1; base += 32) {
        int cnt = min(32, e1 - base);
        if (tid < cnt * NH) {
            int k = tid >> 2, hh = tid & 3;
            float e = als[srcs[base + k] * NH + hh] + ald[n * NH + hh];
            e = (e >= 0.f) ? e : NEG_SLOPE * e;
            s_alpha[k * NH + hh] = __expf(e - s_m[hh]) / s_d[hh];
        }
        __syncthreads();
        for (int k = 0; k < cnt; k++) {
            int s = srcs[base + k];
            acc += s_alpha[k * NH + head] * h[(size_t)s * D1 + tid];
        }
        __syncthreads();
    }

    float v = acc + bias[tid];
    // LayerNorm over 512 + ELU
    rbuf[tid] = v; __syncthreads();
    for (int s = 256; s >= 1; s >>= 1) { if (tid < s) rbuf[tid] += rbuf[tid + s]; __syncthreads(); }
    float mu = rbuf[0] * (1.f / 512.f);
    __syncthreads();
    float dv = v - mu;
    rbuf[tid] = dv * dv; __syncthreads();
    for (int s = 256; s >= 1; s >>= 1) { if (tid < s) rbuf[tid] += rbuf[tid + s]; __syncthreads(); }
    float var = rbuf[0] * (1.f / 512.f);
    float y = dv * rsqrtf(var + LN_EPS) * gamma[tid] + beta[tid];
    out[(size_t)n * D1 + tid] = (y > 0.f) ? y : (__expf(y) - 1.f);
}

// ---------------- tiled fp32 GEMM: C = A[M,K] @ B[K,N] ----------------

#define EPI_NONE 0
#define EPI_BIAS 1
#define EPI_BIAS_RELU 2
#define EPI_RESID 3

template<int EPI>
__global__ void gemm_f32(const float* __restrict__ A, const float* __restrict__ B,
                         const float* __restrict__ bias, float* __restrict__ Cmat,
                         int M, int Ncols, int K, const float* __restrict__ rsc) {
    __shared__ float As[16][68];   // [k][m], padded
    __shared__ float Bs[16][64];   // [k][n]
    int tid = threadIdx.x;                 // 256 threads
    int brow = blockIdx.y * 64;
    int bcol = blockIdx.x * 64;
    int trow = (tid / 16) * 4, tcol = (tid % 16) * 4;
    float acc[4][4] = {};

    for (int k0 = 0; k0 < K; k0 += 16) {
        {   // load A tile 64x16
            int r  = tid >> 2;
            int kk = (tid & 3) << 2;
            int grow = brow + r;
            #pragma unroll
            for (int j = 0; j < 4; j++) {
                int gk = k0 + kk + j;
                As[kk + j][r] = (grow < M && gk < K) ? A[(size_t)grow * K + gk] : 0.f;
            }
            // load B tile 16x64
            int brk = tid >> 4;
            int bc  = (tid & 15) << 2;
            int gk  = k0 + brk;
            if (gk < K) {
                const float4 b4 = *reinterpret_cast<const float4*>(&B[(size_t)gk * Ncols + bcol + bc]);
                Bs[brk][bc] = b4.x; Bs[brk][bc + 1] = b4.y; Bs[brk][bc + 2] = b4.z; Bs[brk][bc + 3] = b4.w;
            } else {
                Bs[brk][bc] = 0.f; Bs[brk][bc + 1] = 0.f; Bs[brk][bc + 2] = 0.f; Bs[brk][bc + 3] = 0.f;
            }
        }
        __syncthreads();
        #pragma unroll
        for (int kk = 0; kk < 16; kk++) {
            float4 a4 = *reinterpret_cast<const float4*>(&As[kk][trow]);
            float4 b4 = *reinterpret_cast<const float4*>(&Bs[kk][tcol]);
            float ra[4] = {a4.x, a4.y, a4.z, a4.w};
            float rb[4] = {b4.x, b4.y, b4.z, b4.w};
            #pragma unroll
            for (int i = 0; i < 4; i++)
                #pragma unroll
                for (int j = 0; j < 4; j++) acc[i][j] += ra[i] * rb[j];
        }
        __syncthreads();
    }

    float rs = (EPI == EPI_RESID) ? *rsc : 0.f;
    #pragma unroll
    for (int i = 0; i < 4; i++) {
        int gr = brow + trow + i;
        if (gr >= M) continue;
        #pragma unroll
        for (int j = 0; j < 4; j++) {
            int gc = bcol + tcol + j;
            if (gc >= Ncols) continue;
            size_t idx = (size_t)gr * Ncols + gc;
            float v = acc[i][j];
            if (EPI == EPI_NONE)      Cmat[idx] = v;
            else if (EPI == EPI_BIAS) Cmat[idx] = v + bias[gc];
            else if (EPI == EPI_BIAS_RELU) { v += bias[gc]; Cmat[idx] = v > 0.f ? v : 0.f; }
            else if (EPI == EPI_RESID)     Cmat[idx] = Cmat[idx] + rs * (v + bias[gc]);
        }
    }
}

// ---------------- classifier tail: out[N,2] ----------------

__global__ void k_classifier(const float* __restrict__ c1, const float* __restrict__ Wc2,
                             const float* __restrict__ bc2, float* __restrict__ out) {
    int n = blockIdx.x, l = threadIdx.x;  // 64 threads (one wave) per node
    float a0 = 0.f, a1 = 0.f;
    for (int k = l; k < D1; k += 64) {
        float v = c1[(size_t)n * D1 + k];
        a0 += v * Wc2[k * 2];
        a1 += v * Wc2[k * 2 + 1];
    }
    for (int s = 32; s >= 1; s >>= 1) { a0 += __shfl_down(a0, s); a1 += __shfl_down(a1, s); }
    if (l == 0) { out[n * 2] = a0 + bc2[0]; out[n * 2 + 1] = a1 + bc2[1]; }
}

// ---------------- launch ----------------

extern "C" void kernel_launch(void* const* d_in, const int* in_sizes, int n_in,
                              void* d_out, int out_size, void* d_ws, size_t ws_size,
                              hipStream_t stream) {
    const float* x   = (const float*)d_in[0];
    const int*   ei  = (const int*)d_in[1];
    const float* W1  = (const float*)d_in[2];
    const float* as1 = (const float*)d_in[3];
    const float* ad1 = (const float*)d_in[4];
    const float* b1  = (const float*)d_in[5];
    const float* g1  = (const float*)d_in[6];
    const float* bn1 = (const float*)d_in[7];
    const float* We1 = (const float*)d_in[8];
    const float* bE1 = (const float*)d_in[9];
    const float* We2 = (const float*)d_in[10];
    const float* bE2 = (const float*)d_in[11];
    const float* Wr  = (const float*)d_in[12];
    const float* br  = (const float*)d_in[13];
    const float* rsc = (const float*)d_in[14];
    const float* W2  = (const float*)d_in[15];
    const float* as2 = (const float*)d_in[16];
    const float* ad2 = (const float*)d_in[17];
    const float* b2  = (const float*)d_in[18];
    const float* g2  = (const float*)d_in[19];
    const float* bn2 = (const float*)d_in[20];
    const float* Wc1 = (const float*)d_in[21];
    const float* bc1 = (const float*)d_in[22];
    const float* Wc2 = (const float*)d_in[23];
    const float* bc2 = (const float*)d_in[24];
    float* out = (float*)d_out;

    char* ws = (char*)d_ws;
    size_t o = 0;
    auto alloc = [&](size_t bytes) { void* p = ws + o; o += (bytes + 255) & ~255ull; return p; };
    float* A    = (float*)alloc((size_t)NNODES * D1 * 4);   // h / tmp / c1
    float* Bb   = (float*)alloc((size_t)NNODES * D1 * 4);   // h1 / h2
    float* Cc   = (float*)alloc((size_t)NNODES * 256 * 4);  // h_comb
    float* als  = (float*)alloc((size_t)NNODES * NH * 4);
    float* ald  = (float*)alloc((size_t)NNODES * NH * 4);
    int* counts = (int*)alloc((NNODES + 1) * 4);
    int* offs   = (int*)alloc((NNODES + 1) * 4);
    int* cursor = (int*)alloc((NNODES + 1) * 4);
    int* srcs   = (int*)alloc((size_t)NTOT * 4);

    // CSR by dst (shared by both GAT layers)
    hipMemsetAsync(counts, 0, NNODES * 4, stream);
    k_count<<<(NTOT + 255) / 256, 256, 0, stream>>>(ei, counts);
    k_scan<<<1, 1024, 0, stream>>>(counts, offs);
    hipMemcpyAsync(cursor, offs, (NNODES + 1) * 4, hipMemcpyDeviceToDevice, stream);
    k_fill<<<(NTOT + 255) / 256, 256, 0, stream>>>(ei, cursor, srcs);

    dim3 blk(256);
    int mby = (NNODES + 63) / 64;  // 782

    // GAT layer 1
    gemm_f32<EPI_NONE><<<dim3(8, mby), blk, 0, stream>>>(x, W1, nullptr, A, NNODES, 512, 182, nullptr);
    k_attn_logits<<<NNODES, 512, 0, stream>>>(A, as1, ad1, als, ald);
    k_gat_aggregate<<<NNODES, 512, 0, stream>>>(A, als, ald, offs, srcs, b1, g1, bn1, Bb);
    // expansion MLP + residual combine
    gemm_f32<EPI_BIAS_RELU><<<dim3(8, mby), blk, 0, stream>>>(Bb, We1, bE1, A, NNODES, 512, 512, nullptr);
    gemm_f32<EPI_BIAS><<<dim3(4, mby), blk, 0, stream>>>(Bb, Wr, br, Cc, NNODES, 256, 512, nullptr);
    gemm_f32<EPI_RESID><<<dim3(4, mby), blk, 0, stream>>>(A, We2, bE2, Cc, NNODES, 256, 512, rsc);
    // GAT layer 2
    gemm_f32<EPI_NONE><<<dim3(8, mby), blk, 0, stream>>>(Cc, W2, nullptr, A, NNODES, 512, 256, nullptr);
    k_attn_logits<<<NNODES, 512, 0, stream>>>(A, as2, ad2, als, ald);
    k_gat_aggregate<<<NNODES, 512, 0, stream>>>(A, als, ald, offs, srcs, b2, g2, bn2, Bb);
    // classifier
    gemm_f32<EPI_BIAS_RELU><<<dim3(8, mby), blk, 0, stream>>>(Bb, Wc1, bc1, A, NNODES, 512, 512, nullptr);
    k_classifier<<<NNODES, 64, 0, stream>>>(A, Wc2, bc2, out);
}

// Round 3
// 1566.563 us; speedup vs baseline: 1.9381x; 1.9381x over previous
//
#include <hip/hip_runtime.h>
#include <hip/hip_bf16.h>
#include <math.h>

#define NNODES 50000
#define NEDGES 500000
#define NTOT   (NEDGES + NNODES)   // 550000 edges incl. self-loops
#define MPAD   50048               // 391 * 128
#define D1     512
#define NH     4
#define LN_EPS 1e-5f
#define NEG_SLOPE 0.2f

typedef __attribute__((ext_vector_type(8))) short short8;
typedef __attribute__((ext_vector_type(4))) float f32x4;
typedef __hip_bfloat16 bf16;

#define GLDS16(g, l) __builtin_amdgcn_global_load_lds( \
    (const __attribute__((address_space(1))) void*)(g), \
    (__attribute__((address_space(3))) void*)(l), 16, 0, 0)

// ---------------- CSR build (counting sort by dst) ----------------

__global__ void k_count(const int* __restrict__ ei, int* __restrict__ counts) {
    int e = blockIdx.x * blockDim.x + threadIdx.x;
    if (e >= NTOT) return;
    int d = (e < NEDGES) ? ei[NEDGES + e] : (e - NEDGES);
    atomicAdd(&counts[d], 1);
}

__global__ void k_scan(const int* __restrict__ counts, int* __restrict__ offs) {
    __shared__ int s[1024];
    int tid = threadIdx.x;
    int running = 0;
    for (int i0 = 0; i0 < NNODES; i0 += 1024) {
        int idx = i0 + tid;
        int v = (idx < NNODES) ? counts[idx] : 0;
        s[tid] = v;
        __syncthreads();
        for (int d = 1; d < 1024; d <<= 1) {
            int t = (tid >= d) ? s[tid - d] : 0;
            __syncthreads();
            s[tid] += t;
            __syncthreads();
        }
        if (idx < NNODES) offs[idx] = running + s[tid] - v;  // exclusive
        int tot = s[1023];
        __syncthreads();
        running += tot;
    }
    if (tid == 0) offs[NNODES] = running;
}

__global__ void k_fill(const int* __restrict__ ei, int* __restrict__ cursor,
                       int* __restrict__ srcs) {
    int e = blockIdx.x * blockDim.x + threadIdx.x;
    if (e >= NTOT) return;
    int s, d;
    if (e < NEDGES) { s = ei[e]; d = ei[NEDGES + e]; }
    else            { s = d = e - NEDGES; }
    int pos = atomicAdd(&cursor[d], 1);
    srcs[pos] = s;
}

// ---------------- conversions ----------------

// W [K][N] f32 -> Wt [N][Kpad] bf16 (zero-pad K)
__global__ void k_wt(const float* __restrict__ W, bf16* __restrict__ Wt,
                     int K, int N, int Kpad) {
    int idx = blockIdx.x * 256 + threadIdx.x;
    if (idx >= N * Kpad) return;
    int n = idx / Kpad, k = idx % Kpad;
    float v = (k < K) ? W[(size_t)k * N + n] : 0.f;
    Wt[idx] = __float2bfloat16(v);
}

// x [50000][182] f32 -> xb [MPAD][192] bf16 zero-padded
__global__ void k_xconv(const float* __restrict__ x, bf16* __restrict__ xb) {
    int idx = blockIdx.x * 256 + threadIdx.x;
    if (idx >= MPAD * 192) return;
    int r = idx / 192, k = idx % 192;
    float v = (r < NNODES && k < 182) ? x[(size_t)r * 182 + k] : 0.f;
    xb[idx] = __float2bfloat16(v);
}

// ---------------- attention logits: als/ald [N,H] ----------------

__global__ void k_attn_logits(const bf16* __restrict__ h, const float* __restrict__ a_s,
                              const float* __restrict__ a_d, float* __restrict__ als,
                              float* __restrict__ ald) {
    int n = blockIdx.x, tid = threadIdx.x;  // 512 threads
    __shared__ float r1[512], r2[512];
    float hv = __bfloat162float(h[(size_t)n * D1 + tid]);
    r1[tid] = hv * a_s[tid];
    r2[tid] = hv * a_d[tid];
    __syncthreads();
    for (int s = 64; s >= 1; s >>= 1) {
        if ((tid & 127) < s) { r1[tid] += r1[tid + s]; r2[tid] += r2[tid + s]; }
        __syncthreads();
    }
    if ((tid & 127) == 0) {
        als[n * NH + (tid >> 7)] = r1[tid];
        ald[n * NH + (tid >> 7)] = r2[tid];
    }
}

// ------------- GAT aggregation + bias + LayerNorm + ELU -------------

__global__ void k_gat_aggregate(const bf16* __restrict__ h, const float* __restrict__ als,
                                const float* __restrict__ ald, const int* __restrict__ offs,
                                const int* __restrict__ srcs, const float* __restrict__ bias,
                                const float* __restrict__ gamma, const float* __restrict__ beta,
                                bf16* __restrict__ out) {
    int n = blockIdx.x, tid = threadIdx.x;  // 512 threads, one block per node
    int e0 = offs[n], e1 = offs[n + 1];
    __shared__ float s_m[NH], s_d[NH];
    __shared__ float s_alpha[32 * NH];
    __shared__ float rbuf[512];

    if (tid < NH) {  // per-head softmax stats over this node's in-edges
        float ad = ald[n * NH + tid];
        float m = -1e30f;
        for (int k = e0; k < e1; k++) {
            float e = als[srcs[k] * NH + tid] + ad;
            e = (e >= 0.f) ? e : NEG_SLOPE * e;
            m = fmaxf(m, e);
        }
        float sum = 0.f;
        for (int k = e0; k < e1; k++) {
            float e = als[srcs[k] * NH + tid] + ad;
            e = (e >= 0.f) ? e : NEG_SLOPE * e;
            sum += __expf(e - m);
        }
        s_m[tid] = m; s_d[tid] = sum;
    }
    __syncthreads();

    float acc = 0.f;
    int head = tid >> 7;
    for (int base = e0; base < e1; base += 32) {
        int cnt = min(32, e1 - base);
        if (tid < cnt * NH) {
            int k = tid >> 2, hh = tid & 3;
            float e = als[srcs[base + k] * NH + hh] + ald[n * NH + hh];
            e = (e >= 0.f) ? e : NEG_SLOPE * e;
            s_alpha[k * NH + hh] = __expf(e - s_m[hh]) / s_d[hh];
        }
        __syncthreads();
        for (int k = 0; k < cnt; k++) {
            int s = srcs[base + k];
            acc += s_alpha[k * NH + head] * __bfloat162float(h[(size_t)s * D1 + tid]);
        }
        __syncthreads();
    }

    float v = acc + bias[tid];
    // LayerNorm over 512 + ELU
    rbuf[tid] = v; __syncthreads();
    for (int s = 256; s >= 1; s >>= 1) { if (tid < s) rbuf[tid] += rbuf[tid + s]; __syncthreads(); }
    float mu = rbuf[0] * (1.f / 512.f);
    __syncthreads();
    float dv = v - mu;
    rbuf[tid] = dv * dv; __syncthreads();
    for (int s = 256; s >= 1; s >>= 1) { if (tid < s) rbuf[tid] += rbuf[tid + s]; __syncthreads(); }
    float var = rbuf[0] * (1.f / 512.f);
    float y = dv * rsqrtf(var + LN_EPS) * gamma[tid] + beta[tid];
    float e = (y > 0.f) ? y : (__expf(y) - 1.f);
    out[(size_t)n * D1 + tid] = __float2bfloat16(e);
}

// ---------------- bf16 MFMA GEMM: C = A[MPAD,K] @ Bt[N,K]^T ----------------
// 128x128 tile, 4 waves (2x2 of 64x64), 16x16x32 bf16 MFMA, K-step 32.
// A, Bt row-major bf16, K % 32 == 0, N % 128 == 0.

#define EPI_BF       0   // C -> bf16
#define EPI_BRELU_BF 1   // relu(C + bias) -> bf16
#define EPI_BIAS_F32 2   // C + bias -> f32
#define EPI_RESID_BF 3   // R + rscale*(C + bias) -> bf16

template<int EPI>
__global__ __launch_bounds__(256) void gemm_bf16(
    const ushort* __restrict__ A, const ushort* __restrict__ Bt,
    const float* __restrict__ bias, bf16* __restrict__ Obf,
    float* __restrict__ Of32, const float* __restrict__ Rf32,
    int Mreal, int N, int K, const float* __restrict__ rsc) {
    __shared__ __align__(16) ushort As[128 * 32];
    __shared__ __align__(16) ushort Bs[128 * 32];
    int tid = threadIdx.x;
    int wave = tid >> 6, lane = tid & 63;
    int brow = blockIdx.y * 128;
    int bcol = blockIdx.x * 128;
    int wm = (wave >> 1) * 64, wn = (wave & 1) * 64;

    f32x4 acc[4][4] = {};

    int ldr = lane >> 2;          // 0..15 row within chunk
    int ldk = (lane & 3) * 8;     // k element offset within 32

    for (int k0 = 0; k0 < K; k0 += 32) {
        if (k0) __syncthreads();   // prev compute done before overwrite
        #pragma unroll
        for (int c2 = 0; c2 < 2; c2++) {
            int c = wave + c2 * 4;            // chunk 0..7 (16 rows each)
            int row = c * 16 + ldr;
            GLDS16(A  + (size_t)(brow + row) * K + k0 + ldk, As + c * 512);
            GLDS16(Bt + (size_t)(bcol + row) * K + k0 + ldk, Bs + c * 512);
        }
        __syncthreads();           // loads landed (compiler drains vmcnt)

        short8 af[4], bfr[4];
        int lr = lane & 15, lk = (lane >> 4) * 8;
        #pragma unroll
        for (int f = 0; f < 4; f++) {
            af[f]  = *reinterpret_cast<const short8*>(&As[(wm + f * 16 + lr) * 32 + lk]);
            bfr[f] = *reinterpret_cast<const short8*>(&Bs[(wn + f * 16 + lr) * 32 + lk]);
        }
        #pragma unroll
        for (int fm = 0; fm < 4; fm++)
            #pragma unroll
            for (int fn = 0; fn < 4; fn++)
                acc[fm][fn] = __builtin_amdgcn_mfma_f32_16x16x32_bf16(
                    af[fm], bfr[fn], acc[fm][fn], 0, 0, 0);
    }

    float rs = (EPI == EPI_RESID_BF) ? *rsc : 0.f;
    #pragma unroll
    for (int fm = 0; fm < 4; fm++) {
        int row0 = brow + wm + fm * 16 + (lane >> 4) * 4;
        #pragma unroll
        for (int fn = 0; fn < 4; fn++) {
            int col = bcol + wn + fn * 16 + (lane & 15);
            #pragma unroll
            for (int r = 0; r < 4; r++) {
                int row = row0 + r;
                if (row >= Mreal) continue;
                size_t idx = (size_t)row * N + col;
                float v = acc[fm][fn][r];
                if (EPI == EPI_BF) {
                    Obf[idx] = __float2bfloat16(v);
                } else if (EPI == EPI_BRELU_BF) {
                    v += bias[col]; v = v > 0.f ? v : 0.f;
                    Obf[idx] = __float2bfloat16(v);
                } else if (EPI == EPI_BIAS_F32) {
                    Of32[idx] = v + bias[col];
                } else {
                    Obf[idx] = __float2bfloat16(Rf32[idx] + rs * (v + bias[col]));
                }
            }
        }
    }
}

// ---------------- classifier tail: out[N,2] ----------------

__global__ void k_classifier(const bf16* __restrict__ c1, const float* __restrict__ Wc2,
                             const float* __restrict__ bc2, float* __restrict__ out) {
    int n = blockIdx.x, l = threadIdx.x;  // 64 threads (one wave) per node
    float a0 = 0.f, a1 = 0.f;
    for (int k = l; k < D1; k += 64) {
        float v = __bfloat162float(c1[(size_t)n * D1 + k]);
        a0 += v * Wc2[k * 2];
        a1 += v * Wc2[k * 2 + 1];
    }
    for (int s = 32; s >= 1; s >>= 1) { a0 += __shfl_down(a0, s); a1 += __shfl_down(a1, s); }
    if (l == 0) { out[n * 2] = a0 + bc2[0]; out[n * 2 + 1] = a1 + bc2[1]; }
}

// ---------------- launch ----------------

extern "C" void kernel_launch(void* const* d_in, const int* in_sizes, int n_in,
                              void* d_out, int out_size, void* d_ws, size_t ws_size,
                              hipStream_t stream) {
    const float* x   = (const float*)d_in[0];
    const int*   ei  = (const int*)d_in[1];
    const float* W1  = (const float*)d_in[2];
    const float* as1 = (const float*)d_in[3];
    const float* ad1 = (const float*)d_in[4];
    const float* b1  = (const float*)d_in[5];
    const float* g1  = (const float*)d_in[6];
    const float* bn1 = (const float*)d_in[7];
    const float* We1 = (const float*)d_in[8];
    const float* bE1 = (const float*)d_in[9];
    const float* We2 = (const float*)d_in[10];
    const float* bE2 = (const float*)d_in[11];
    const float* Wr  = (const float*)d_in[12];
    const float* br  = (const float*)d_in[13];
    const float* rsc = (const float*)d_in[14];
    const float* W2  = (const float*)d_in[15];
    const float* as2 = (const float*)d_in[16];
    const float* ad2 = (const float*)d_in[17];
    const float* b2  = (const float*)d_in[18];
    const float* g2  = (const float*)d_in[19];
    const float* bn2 = (const float*)d_in[20];
    const float* Wc1 = (const float*)d_in[21];
    const float* bc1 = (const float*)d_in[22];
    const float* Wc2 = (const float*)d_in[23];
    const float* bc2 = (const float*)d_in[24];
    float* out = (float*)d_out;

    char* ws = (char*)d_ws;
    size_t o = 0;
    auto alloc = [&](size_t bytes) { void* p = ws + o; o += (bytes + 255) & ~255ull; return p; };
    bf16* xb    = (bf16*)alloc((size_t)MPAD * 192 * 2);
    bf16* bufA  = (bf16*)alloc((size_t)MPAD * D1 * 2);   // h (layer1), h2raw (layer2)
    bf16* bufB  = (bf16*)alloc((size_t)MPAD * D1 * 2);   // h1, h2
    bf16* bufC  = (bf16*)alloc((size_t)MPAD * D1 * 2);   // t (expansion), c1
    float* hcf  = (float*)alloc((size_t)MPAD * 256 * 4); // h_comb f32 partial
    bf16* hcb   = (bf16*)alloc((size_t)MPAD * 256 * 2);  // h_comb bf16
    bf16* W1t   = (bf16*)alloc((size_t)512 * 192 * 2);
    bf16* We1t  = (bf16*)alloc((size_t)512 * 512 * 2);
    bf16* We2t  = (bf16*)alloc((size_t)256 * 512 * 2);
    bf16* Wrt   = (bf16*)alloc((size_t)256 * 512 * 2);
    bf16* W2t   = (bf16*)alloc((size_t)512 * 256 * 2);
    bf16* Wc1t  = (bf16*)alloc((size_t)512 * 512 * 2);
    float* als  = (float*)alloc((size_t)NNODES * NH * 4);
    float* ald  = (float*)alloc((size_t)NNODES * NH * 4);
    int* counts = (int*)alloc((NNODES + 1) * 4);
    int* offs   = (int*)alloc((NNODES + 1) * 4);
    int* cursor = (int*)alloc((NNODES + 1) * 4);
    int* srcs   = (int*)alloc((size_t)NTOT * 4);

    // CSR by dst (shared by both GAT layers)
    hipMemsetAsync(counts, 0, NNODES * 4, stream);
    k_count<<<(NTOT + 255) / 256, 256, 0, stream>>>(ei, counts);
    k_scan<<<1, 1024, 0, stream>>>(counts, offs);
    hipMemcpyAsync(cursor, offs, (NNODES + 1) * 4, hipMemcpyDeviceToDevice, stream);
    k_fill<<<(NTOT + 255) / 256, 256, 0, stream>>>(ei, cursor, srcs);

    // weight conversion (transposed bf16)
    k_wt<<<(512 * 192 + 255) / 256, 256, 0, stream>>>(W1,  W1t,  182, 512, 192);
    k_wt<<<(512 * 512 + 255) / 256, 256, 0, stream>>>(We1, We1t, 512, 512, 512);
    k_wt<<<(256 * 512 + 255) / 256, 256, 0, stream>>>(We2, We2t, 512, 256, 512);
    k_wt<<<(256 * 512 + 255) / 256, 256, 0, stream>>>(Wr,  Wrt,  512, 256, 512);
    k_wt<<<(512 * 256 + 255) / 256, 256, 0, stream>>>(W2,  W2t,  256, 512, 256);
    k_wt<<<(512 * 512 + 255) / 256, 256, 0, stream>>>(Wc1, Wc1t, 512, 512, 512);
    k_xconv<<<(MPAD * 192 + 255) / 256, 256, 0, stream>>>(x, xb);

    dim3 blk(256);
    dim3 g512(4, MPAD / 128), g256(2, MPAD / 128);

    // GAT layer 1: h = x @ W1
    gemm_bf16<EPI_BF><<<g512, blk, 0, stream>>>((const ushort*)xb, (const ushort*)W1t,
        nullptr, bufA, nullptr, nullptr, NNODES, 512, 192, nullptr);
    k_attn_logits<<<NNODES, 512, 0, stream>>>(bufA, as1, ad1, als, ald);
    k_gat_aggregate<<<NNODES, 512, 0, stream>>>(bufA, als, ald, offs, srcs, b1, g1, bn1, bufB);

    // expansion MLP + residual combine
    gemm_bf16<EPI_BRELU_BF><<<g512, blk, 0, stream>>>((const ushort*)bufB, (const ushort*)We1t,
        bE1, bufC, nullptr, nullptr, NNODES, 512, 512, nullptr);
    gemm_bf16<EPI_BIAS_F32><<<g256, blk, 0, stream>>>((const ushort*)bufB, (const ushort*)Wrt,
        br, nullptr, hcf, nullptr, NNODES, 256, 512, nullptr);
    gemm_bf16<EPI_RESID_BF><<<g256, blk, 0, stream>>>((const ushort*)bufC, (const ushort*)We2t,
        bE2, hcb, nullptr, hcf, NNODES, 256, 512, rsc);

    // GAT layer 2: h = h_comb @ W2
    gemm_bf16<EPI_BF><<<g512, blk, 0, stream>>>((const ushort*)hcb, (const ushort*)W2t,
        nullptr, bufA, nullptr, nullptr, NNODES, 512, 256, nullptr);
    k_attn_logits<<<NNODES, 512, 0, stream>>>(bufA, as2, ad2, als, ald);
    k_gat_aggregate<<<NNODES, 512, 0, stream>>>(bufA, als, ald, offs, srcs, b2, g2, bn2, bufB);

    // classifier
    gemm_bf16<EPI_BRELU_BF><<<g512, blk, 0, stream>>>((const ushort*)bufB, (const ushort*)Wc1t,
        bc1, bufC, nullptr, nullptr, NNODES, 512, 512, nullptr);
    k_classifier<<<NNODES, 64, 0, stream>>>(bufC, Wc2, bc2, out);
}

// Round 4
// 705.872 us; speedup vs baseline: 4.3012x; 2.2193x over previous
//
#include <hip/hip_runtime.h>
#include <hip/hip_bf16.h>
#include <math.h>

#define NNODES 50000
#define NEDGES 500000
#define NTOT   (NEDGES + NNODES)   // 550000 edges incl. self-loops
#define MPAD   50048               // 391 * 128
#define D1     512
#define NH     4
#define LN_EPS 1e-5f
#define NEG_SLOPE 0.2f

typedef __attribute__((ext_vector_type(8))) short short8;
typedef __attribute__((ext_vector_type(4))) float f32x4;
typedef __hip_bfloat16 bf16;

#define GLDS16(g, l) __builtin_amdgcn_global_load_lds( \
    (const __attribute__((address_space(1))) void*)(g), \
    (__attribute__((address_space(3))) void*)(l), 16, 0, 0)

__device__ __forceinline__ float bf2f(short u) {
    unsigned int x = ((unsigned int)(unsigned short)u) << 16;
    return __uint_as_float(x);
}
__device__ __forceinline__ short f2bf(float f) {   // RNE
    unsigned int x = __float_as_uint(f);
    unsigned int r = (x + 0x7fffu + ((x >> 16) & 1u)) >> 16;
    return (short)r;
}
__device__ __forceinline__ float leaky(float e) {
    return (e >= 0.f) ? e : NEG_SLOPE * e;
}

// ---------------- CSR build (counting sort by dst) ----------------

__global__ void k_count(const int* __restrict__ ei, int* __restrict__ counts) {
    int e = blockIdx.x * blockDim.x + threadIdx.x;
    if (e >= NTOT) return;
    int d = (e < NEDGES) ? ei[NEDGES + e] : (e - NEDGES);
    atomicAdd(&counts[d], 1);
}

__global__ void k_scan(const int* __restrict__ counts, int* __restrict__ offs) {
    __shared__ int s[1024];
    int tid = threadIdx.x;
    int running = 0;
    for (int i0 = 0; i0 < NNODES; i0 += 1024) {
        int idx = i0 + tid;
        int v = (idx < NNODES) ? counts[idx] : 0;
        s[tid] = v;
        __syncthreads();
        for (int d = 1; d < 1024; d <<= 1) {
            int t = (tid >= d) ? s[tid - d] : 0;
            __syncthreads();
            s[tid] += t;
            __syncthreads();
        }
        if (idx < NNODES) offs[idx] = running + s[tid] - v;  // exclusive
        int tot = s[1023];
        __syncthreads();
        running += tot;
    }
    if (tid == 0) offs[NNODES] = running;
}

__global__ void k_fill(const int* __restrict__ ei, int* __restrict__ cursor,
                       int* __restrict__ srcs) {
    int e = blockIdx.x * blockDim.x + threadIdx.x;
    if (e >= NTOT) return;
    int s, d;
    if (e < NEDGES) { s = ei[e]; d = ei[NEDGES + e]; }
    else            { s = d = e - NEDGES; }
    int pos = atomicAdd(&cursor[d], 1);
    srcs[pos] = s;
}

// ---------------- conversions ----------------

// W [K][N] f32 -> Wt [N][Kpad] bf16 (zero-pad K)
__global__ void k_wt(const float* __restrict__ W, bf16* __restrict__ Wt,
                     int K, int N, int Kpad) {
    int idx = blockIdx.x * 256 + threadIdx.x;
    if (idx >= N * Kpad) return;
    int n = idx / Kpad, k = idx % Kpad;
    float v = (k < K) ? W[(size_t)k * N + n] : 0.f;
    Wt[idx] = __float2bfloat16(v);
}

// x [50000][182] f32 -> xb [MPAD][192] bf16 zero-padded
__global__ void k_xconv(const float* __restrict__ x, bf16* __restrict__ xb) {
    int idx = blockIdx.x * 256 + threadIdx.x;
    if (idx >= MPAD * 192) return;
    int r = idx / 192, k = idx % 192;
    float v = (r < NNODES && k < 182) ? x[(size_t)r * 182 + k] : 0.f;
    xb[idx] = __float2bfloat16(v);
}

// ---------------- attention logits: als/ald [N,H] (one wave per node) --------

__global__ __launch_bounds__(256) void k_attn_logits(
        const bf16* __restrict__ h, const float* __restrict__ a_s,
        const float* __restrict__ a_d, float* __restrict__ als,
        float* __restrict__ ald) {
    int tid = threadIdx.x;
    int n = blockIdx.x * 4 + (tid >> 6);
    if (n >= NNODES) return;
    int lane = tid & 63;
    int ch0 = lane * 8;
    short8 hv = *reinterpret_cast<const short8*>(&h[(size_t)n * D1 + ch0]);
    float s1 = 0.f, s2 = 0.f;
    #pragma unroll
    for (int j = 0; j < 8; j++) {
        float v = bf2f(hv[j]);
        s1 += v * a_s[ch0 + j];
        s2 += v * a_d[ch0 + j];
    }
    #pragma unroll
    for (int o = 1; o < 16; o <<= 1) {
        s1 += __shfl_xor(s1, o);
        s2 += __shfl_xor(s2, o);
    }
    if ((lane & 15) == 0) {
        int head = lane >> 4;
        als[n * NH + head] = s1;
        ald[n * NH + head] = s2;
    }
}

// ------ GAT aggregation + bias + LayerNorm + ELU (one wave per node) --------

__global__ __launch_bounds__(256) void k_gat_aggregate(
        const bf16* __restrict__ h, const float* __restrict__ als,
        const float* __restrict__ ald, const int* __restrict__ offs,
        const int* __restrict__ srcs, const float* __restrict__ bias,
        const float* __restrict__ gamma, const float* __restrict__ beta,
        bf16* __restrict__ out) {
    int tid = threadIdx.x;
    int n = blockIdx.x * 4 + (tid >> 6);
    if (n >= NNODES) return;
    int lane = tid & 63;
    int head = lane >> 4;
    int ch0 = lane * 8;
    int e0 = offs[n], e1 = offs[n + 1];
    float adh = ald[n * NH + head];

    // softmax stats, edge-parallel across the 16 lanes of this head group
    float m = -1e30f;
    for (int k = e0 + (lane & 15); k < e1; k += 16)
        m = fmaxf(m, leaky(als[srcs[k] * NH + head] + adh));
    #pragma unroll
    for (int o = 1; o < 16; o <<= 1) m = fmaxf(m, __shfl_xor(m, o));
    float d = 0.f;
    for (int k = e0 + (lane & 15); k < e1; k += 16)
        d += __expf(leaky(als[srcs[k] * NH + head] + adh) - m);
    #pragma unroll
    for (int o = 1; o < 16; o <<= 1) d += __shfl_xor(d, o);
    float dinv = 1.f / d;

    // weighted aggregation, 4 edges in flight
    float acc[8] = {};
    for (int base = e0; base < e1; base += 64) {
        int cnt = min(64, e1 - base);
        int sv = (base + lane < e1) ? srcs[base + lane] : 0;
        int k = 0;
        for (; k + 4 <= cnt; k += 4) {
            int s0 = __shfl(sv, k),     s1 = __shfl(sv, k + 1);
            int s2 = __shfl(sv, k + 2), s3 = __shfl(sv, k + 3);
            float a0 = als[s0 * NH + head], a1 = als[s1 * NH + head];
            float a2 = als[s2 * NH + head], a3 = als[s3 * NH + head];
            short8 h0 = *reinterpret_cast<const short8*>(&h[(size_t)s0 * D1 + ch0]);
            short8 h1 = *reinterpret_cast<const short8*>(&h[(size_t)s1 * D1 + ch0]);
            short8 h2 = *reinterpret_cast<const short8*>(&h[(size_t)s2 * D1 + ch0]);
            short8 h3 = *reinterpret_cast<const short8*>(&h[(size_t)s3 * D1 + ch0]);
            float p0 = __expf(leaky(a0 + adh) - m) * dinv;
            float p1 = __expf(leaky(a1 + adh) - m) * dinv;
            float p2 = __expf(leaky(a2 + adh) - m) * dinv;
            float p3 = __expf(leaky(a3 + adh) - m) * dinv;
            #pragma unroll
            for (int j = 0; j < 8; j++)
                acc[j] += p0 * bf2f(h0[j]) + p1 * bf2f(h1[j])
                        + p2 * bf2f(h2[j]) + p3 * bf2f(h3[j]);
        }
        for (; k < cnt; k++) {
            int s0 = __shfl(sv, k);
            float p0 = __expf(leaky(als[s0 * NH + head] + adh) - m) * dinv;
            short8 h0 = *reinterpret_cast<const short8*>(&h[(size_t)s0 * D1 + ch0]);
            #pragma unroll
            for (int j = 0; j < 8; j++) acc[j] += p0 * bf2f(h0[j]);
        }
    }

    // bias + LayerNorm(512) + ELU, wave-wide shuffle reduce
    float v[8];
    float ps = 0.f;
    #pragma unroll
    for (int j = 0; j < 8; j++) { v[j] = acc[j] + bias[ch0 + j]; ps += v[j]; }
    #pragma unroll
    for (int o = 1; o < 64; o <<= 1) ps += __shfl_xor(ps, o);
    float mu = ps * (1.f / 512.f);
    float qs = 0.f;
    #pragma unroll
    for (int j = 0; j < 8; j++) { float dvj = v[j] - mu; qs += dvj * dvj; }
    #pragma unroll
    for (int o = 1; o < 64; o <<= 1) qs += __shfl_xor(qs, o);
    float rstd = rsqrtf(qs * (1.f / 512.f) + LN_EPS);

    short8 ov;
    #pragma unroll
    for (int j = 0; j < 8; j++) {
        float y = (v[j] - mu) * rstd * gamma[ch0 + j] + beta[ch0 + j];
        float e = (y > 0.f) ? y : (__expf(y) - 1.f);
        ov[j] = f2bf(e);
    }
    *reinterpret_cast<short8*>(&out[(size_t)n * D1 + ch0]) = ov;
}

// ---------------- bf16 MFMA GEMM: C = A[MPAD,K] @ Bt[N,K]^T ----------------
// 128x128 tile, 4 waves (2x2 of 64x64), 16x16x32 bf16 MFMA, K-step 32.

#define EPI_BF       0   // C -> bf16
#define EPI_BRELU_BF 1   // relu(C + bias) -> bf16
#define EPI_BIAS_F32 2   // C + bias -> f32
#define EPI_RESID_BF 3   // R + rscale*(C + bias) -> bf16

template<int EPI>
__global__ __launch_bounds__(256) void gemm_bf16(
    const ushort* __restrict__ A, const ushort* __restrict__ Bt,
    const float* __restrict__ bias, bf16* __restrict__ Obf,
    float* __restrict__ Of32, const float* __restrict__ Rf32,
    int Mreal, int N, int K, const float* __restrict__ rsc) {
    __shared__ __align__(16) ushort As[128 * 32];
    __shared__ __align__(16) ushort Bs[128 * 32];
    int tid = threadIdx.x;
    int wave = tid >> 6, lane = tid & 63;
    int brow = blockIdx.y * 128;
    int bcol = blockIdx.x * 128;
    int wm = (wave >> 1) * 64, wn = (wave & 1) * 64;

    f32x4 acc[4][4] = {};

    int ldr = lane >> 2;          // 0..15 row within chunk
    int ldk = (lane & 3) * 8;     // k element offset within 32

    for (int k0 = 0; k0 < K; k0 += 32) {
        if (k0) __syncthreads();   // prev compute done before overwrite
        #pragma unroll
        for (int c2 = 0; c2 < 2; c2++) {
            int c = wave + c2 * 4;            // chunk 0..7 (16 rows each)
            int row = c * 16 + ldr;
            GLDS16(A  + (size_t)(brow + row) * K + k0 + ldk, As + c * 512);
            GLDS16(Bt + (size_t)(bcol + row) * K + k0 + ldk, Bs + c * 512);
        }
        __syncthreads();           // loads landed (compiler drains vmcnt)

        short8 af[4], bfr[4];
        int lr = lane & 15, lk = (lane >> 4) * 8;
        #pragma unroll
        for (int f = 0; f < 4; f++) {
            af[f]  = *reinterpret_cast<const short8*>(&As[(wm + f * 16 + lr) * 32 + lk]);
            bfr[f] = *reinterpret_cast<const short8*>(&Bs[(wn + f * 16 + lr) * 32 + lk]);
        }
        #pragma unroll
        for (int fm = 0; fm < 4; fm++)
            #pragma unroll
            for (int fn = 0; fn < 4; fn++)
                acc[fm][fn] = __builtin_amdgcn_mfma_f32_16x16x32_bf16(
                    af[fm], bfr[fn], acc[fm][fn], 0, 0, 0);
    }

    float rs = (EPI == EPI_RESID_BF) ? *rsc : 0.f;
    #pragma unroll
    for (int fm = 0; fm < 4; fm++) {
        int row0 = brow + wm + fm * 16 + (lane >> 4) * 4;
        #pragma unroll
        for (int fn = 0; fn < 4; fn++) {
            int col = bcol + wn + fn * 16 + (lane & 15);
            #pragma unroll
            for (int r = 0; r < 4; r++) {
                int row = row0 + r;
                if (row >= Mreal) continue;
                size_t idx = (size_t)row * N + col;
                float v = acc[fm][fn][r];
                if (EPI == EPI_BF) {
                    Obf[idx] = __float2bfloat16(v);
                } else if (EPI == EPI_BRELU_BF) {
                    v += bias[col]; v = v > 0.f ? v : 0.f;
                    Obf[idx] = __float2bfloat16(v);
                } else if (EPI == EPI_BIAS_F32) {
                    Of32[idx] = v + bias[col];
                } else {
                    Obf[idx] = __float2bfloat16(Rf32[idx] + rs * (v + bias[col]));
                }
            }
        }
    }
}

// ---------------- classifier tail: out[N,2] ----------------

__global__ void k_classifier(const bf16* __restrict__ c1, const float* __restrict__ Wc2,
                             const float* __restrict__ bc2, float* __restrict__ out) {
    int n = blockIdx.x, l = threadIdx.x;  // 64 threads (one wave) per node
    float a0 = 0.f, a1 = 0.f;
    for (int k = l; k < D1; k += 64) {
        float v = __bfloat162float(c1[(size_t)n * D1 + k]);
        a0 += v * Wc2[k * 2];
        a1 += v * Wc2[k * 2 + 1];
    }
    for (int s = 32; s >= 1; s >>= 1) { a0 += __shfl_down(a0, s); a1 += __shfl_down(a1, s); }
    if (l == 0) { out[n * 2] = a0 + bc2[0]; out[n * 2 + 1] = a1 + bc2[1]; }
}

// ---------------- launch ----------------

extern "C" void kernel_launch(void* const* d_in, const int* in_sizes, int n_in,
                              void* d_out, int out_size, void* d_ws, size_t ws_size,
                              hipStream_t stream) {
    const float* x   = (const float*)d_in[0];
    const int*   ei  = (const int*)d_in[1];
    const float* W1  = (const float*)d_in[2];
    const float* as1 = (const float*)d_in[3];
    const float* ad1 = (const float*)d_in[4];
    const float* b1  = (const float*)d_in[5];
    const float* g1  = (const float*)d_in[6];
    const float* bn1 = (const float*)d_in[7];
    const float* We1 = (const float*)d_in[8];
    const float* bE1 = (const float*)d_in[9];
    const float* We2 = (const float*)d_in[10];
    const float* bE2 = (const float*)d_in[11];
    const float* Wr  = (const float*)d_in[12];
    const float* br  = (const float*)d_in[13];
    const float* rsc = (const float*)d_in[14];
    const float* W2  = (const float*)d_in[15];
    const float* as2 = (const float*)d_in[16];
    const float* ad2 = (const float*)d_in[17];
    const float* b2  = (const float*)d_in[18];
    const float* g2  = (const float*)d_in[19];
    const float* bn2 = (const float*)d_in[20];
    const float* Wc1 = (const float*)d_in[21];
    const float* bc1 = (const float*)d_in[22];
    const float* Wc2 = (const float*)d_in[23];
    const float* bc2 = (const float*)d_in[24];
    float* out = (float*)d_out;

    char* ws = (char*)d_ws;
    size_t o = 0;
    auto alloc = [&](size_t bytes) { void* p = ws + o; o += (bytes + 255) & ~255ull; return p; };
    bf16* xb    = (bf16*)alloc((size_t)MPAD * 192 * 2);
    bf16* bufA  = (bf16*)alloc((size_t)MPAD * D1 * 2);   // h (layer1), h2raw (layer2)
    bf16* bufB  = (bf16*)alloc((size_t)MPAD * D1 * 2);   // h1, h2
    bf16* bufC  = (bf16*)alloc((size_t)MPAD * D1 * 2);   // t (expansion), c1
    float* hcf  = (float*)alloc((size_t)MPAD * 256 * 4); // h_comb f32 partial
    bf16* hcb   = (bf16*)alloc((size_t)MPAD * 256 * 2);  // h_comb bf16
    bf16* W1t   = (bf16*)alloc((size_t)512 * 192 * 2);
    bf16* We1t  = (bf16*)alloc((size_t)512 * 512 * 2);
    bf16* We2t  = (bf16*)alloc((size_t)256 * 512 * 2);
    bf16* Wrt   = (bf16*)alloc((size_t)256 * 512 * 2);
    bf16* W2t   = (bf16*)alloc((size_t)512 * 256 * 2);
    bf16* Wc1t  = (bf16*)alloc((size_t)512 * 512 * 2);
    float* als  = (float*)alloc((size_t)NNODES * NH * 4);
    float* ald  = (float*)alloc((size_t)NNODES * NH * 4);
    int* counts = (int*)alloc((NNODES + 1) * 4);
    int* offs   = (int*)alloc((NNODES + 1) * 4);
    int* cursor = (int*)alloc((NNODES + 1) * 4);
    int* srcs   = (int*)alloc((size_t)NTOT * 4);

    // CSR by dst (shared by both GAT layers)
    hipMemsetAsync(counts, 0, NNODES * 4, stream);
    k_count<<<(NTOT + 255) / 256, 256, 0, stream>>>(ei, counts);
    k_scan<<<1, 1024, 0, stream>>>(counts, offs);
    hipMemcpyAsync(cursor, offs, (NNODES + 1) * 4, hipMemcpyDeviceToDevice, stream);
    k_fill<<<(NTOT + 255) / 256, 256, 0, stream>>>(ei, cursor, srcs);

    // weight conversion (transposed bf16)
    k_wt<<<(512 * 192 + 255) / 256, 256, 0, stream>>>(W1,  W1t,  182, 512, 192);
    k_wt<<<(512 * 512 + 255) / 256, 256, 0, stream>>>(We1, We1t, 512, 512, 512);
    k_wt<<<(256 * 512 + 255) / 256, 256, 0, stream>>>(We2, We2t, 512, 256, 512);
    k_wt<<<(256 * 512 + 255) / 256, 256, 0, stream>>>(Wr,  Wrt,  512, 256, 512);
    k_wt<<<(512 * 256 + 255) / 256, 256, 0, stream>>>(W2,  W2t,  256, 512, 256);
    k_wt<<<(512 * 512 + 255) / 256, 256, 0, stream>>>(Wc1, Wc1t, 512, 512, 512);
    k_xconv<<<(MPAD * 192 + 255) / 256, 256, 0, stream>>>(x, xb);

    dim3 blk(256);
    dim3 g512(4, MPAD / 128), g256(2, MPAD / 128);
    int nwb = (NNODES + 3) / 4;   // wave-per-node kernels: 4 waves/block

    // GAT layer 1: h = x @ W1
    gemm_bf16<EPI_BF><<<g512, blk, 0, stream>>>((const ushort*)xb, (const ushort*)W1t,
        nullptr, bufA, nullptr, nullptr, NNODES, 512, 192, nullptr);
    k_attn_logits<<<nwb, blk, 0, stream>>>(bufA, as1, ad1, als, ald);
    k_gat_aggregate<<<nwb, blk, 0, stream>>>(bufA, als, ald, offs, srcs, b1, g1, bn1, bufB);

    // expansion MLP + residual combine
    gemm_bf16<EPI_BRELU_BF><<<g512, blk, 0, stream>>>((const ushort*)bufB, (const ushort*)We1t,
        bE1, bufC, nullptr, nullptr, NNODES, 512, 512, nullptr);
    gemm_bf16<EPI_BIAS_F32><<<g256, blk, 0, stream>>>((const ushort*)bufB, (const ushort*)Wrt,
        br, nullptr, hcf, nullptr, NNODES, 256, 512, nullptr);
    gemm_bf16<EPI_RESID_BF><<<g256, blk, 0, stream>>>((const ushort*)bufC, (const ushort*)We2t,
        bE2, hcb, nullptr, hcf, NNODES, 256, 512, rsc);

    // GAT layer 2: h = h_comb @ W2
    gemm_bf16<EPI_BF><<<g512, blk, 0, stream>>>((const ushort*)hcb, (const ushort*)W2t,
        nullptr, bufA, nullptr, nullptr, NNODES, 512, 256, nullptr);
    k_attn_logits<<<nwb, blk, 0, stream>>>(bufA, as2, ad2, als, ald);
    k_gat_aggregate<<<nwb, blk, 0, stream>>>(bufA, als, ald, offs, srcs, b2, g2, bn2, bufB);

    // classifier
    gemm_bf16<EPI_BRELU_BF><<<g512, blk, 0, stream>>>((const ushort*)bufB, (const ushort*)Wc1t,
        bc1, bufC, nullptr, nullptr, NNODES, 512, 512, nullptr);
    k_classifier<<<NNODES, 64, 0, stream>>>(bufC, Wc2, bc2, out);
}

// Round 5
// 647.185 us; speedup vs baseline: 4.6912x; 1.0907x over previous
//
#include <hip/hip_runtime.h>
#include <hip/hip_bf16.h>
#include <math.h>

#define NNODES 50000
#define NEDGES 500000
#define NTOT   (NEDGES + NNODES)   // 550000 edges incl. self-loops
#define MPAD   50048               // 391 * 128
#define D1     512
#define NH     4
#define LN_EPS 1e-5f
#define NEG_SLOPE 0.2f

typedef __attribute__((ext_vector_type(8))) short short8;
typedef __attribute__((ext_vector_type(4))) float f32x4;
typedef __hip_bfloat16 bf16;

#define GLDS16(g, l) __builtin_amdgcn_global_load_lds( \
    (const __attribute__((address_space(1))) void*)(g), \
    (__attribute__((address_space(3))) void*)(l), 16, 0, 0)

__device__ __forceinline__ float bf2f(short u) {
    unsigned int x = ((unsigned int)(unsigned short)u) << 16;
    return __uint_as_float(x);
}
__device__ __forceinline__ short f2bf(float f) {   // RNE
    unsigned int x = __float_as_uint(f);
    unsigned int r = (x + 0x7fffu + ((x >> 16) & 1u)) >> 16;
    return (short)r;
}
__device__ __forceinline__ float leaky(float e) {
    return (e >= 0.f) ? e : NEG_SLOPE * e;
}

// ---------------- CSR build (counting sort by dst) ----------------

__global__ void k_count(const int* __restrict__ ei, int* __restrict__ counts) {
    int e = blockIdx.x * blockDim.x + threadIdx.x;
    if (e >= NTOT) return;
    int d = (e < NEDGES) ? ei[NEDGES + e] : (e - NEDGES);
    atomicAdd(&counts[d], 1);
}

__global__ void k_scan(const int* __restrict__ counts, int* __restrict__ offs) {
    __shared__ int s[1024];
    int tid = threadIdx.x;
    int running = 0;
    for (int i0 = 0; i0 < NNODES; i0 += 1024) {
        int idx = i0 + tid;
        int v = (idx < NNODES) ? counts[idx] : 0;
        s[tid] = v;
        __syncthreads();
        for (int d = 1; d < 1024; d <<= 1) {
            int t = (tid >= d) ? s[tid - d] : 0;
            __syncthreads();
            s[tid] += t;
            __syncthreads();
        }
        if (idx < NNODES) offs[idx] = running + s[tid] - v;  // exclusive
        int tot = s[1023];
        __syncthreads();
        running += tot;
    }
    if (tid == 0) offs[NNODES] = running;
}

__global__ void k_fill(const int* __restrict__ ei, int* __restrict__ cursor,
                       int* __restrict__ srcs) {
    int e = blockIdx.x * blockDim.x + threadIdx.x;
    if (e >= NTOT) return;
    int s, d;
    if (e < NEDGES) { s = ei[e]; d = ei[NEDGES + e]; }
    else            { s = d = e - NEDGES; }
    int pos = atomicAdd(&cursor[d], 1);
    srcs[pos] = s;
}

// ---------------- conversions ----------------

__global__ void k_wt(const float* __restrict__ W, bf16* __restrict__ Wt,
                     int K, int N, int Kpad) {
    int idx = blockIdx.x * 256 + threadIdx.x;
    if (idx >= N * Kpad) return;
    int n = idx / Kpad, k = idx % Kpad;
    float v = (k < K) ? W[(size_t)k * N + n] : 0.f;
    Wt[idx] = __float2bfloat16(v);
}

__global__ void k_xconv(const float* __restrict__ x, bf16* __restrict__ xb) {
    int idx = blockIdx.x * 256 + threadIdx.x;
    if (idx >= MPAD * 192) return;
    int r = idx / 192, k = idx % 192;
    float v = (r < NNODES && k < 182) ? x[(size_t)r * 182 + k] : 0.f;
    xb[idx] = __float2bfloat16(v);
}

// ---------------- attention logits: als/ald [N,H] (one wave per node) --------

__global__ __launch_bounds__(256) void k_attn_logits(
        const bf16* __restrict__ h, const float* __restrict__ a_s,
        const float* __restrict__ a_d, float* __restrict__ als,
        float* __restrict__ ald) {
    int tid = threadIdx.x;
    int n = blockIdx.x * 4 + (tid >> 6);
    if (n >= NNODES) return;
    int lane = tid & 63;
    int ch0 = lane * 8;
    short8 hv = *reinterpret_cast<const short8*>(&h[(size_t)n * D1 + ch0]);
    float s1 = 0.f, s2 = 0.f;
    #pragma unroll
    for (int j = 0; j < 8; j++) {
        float v = bf2f(hv[j]);
        s1 += v * a_s[ch0 + j];
        s2 += v * a_d[ch0 + j];
    }
    #pragma unroll
    for (int o = 1; o < 16; o <<= 1) {
        s1 += __shfl_xor(s1, o);
        s2 += __shfl_xor(s2, o);
    }
    if ((lane & 15) == 0) {
        int head = lane >> 4;
        als[n * NH + head] = s1;
        ald[n * NH + head] = s2;
    }
}

// -------- per-edge softmax alpha (one wave per node, edge-parallel) ---------

__global__ __launch_bounds__(256) void k_edge_alpha(
        const float* __restrict__ als, const float* __restrict__ ald,
        const int* __restrict__ offs, const int* __restrict__ srcs,
        float* __restrict__ alpha) {
    int tid = threadIdx.x;
    int n = blockIdx.x * 4 + (tid >> 6);
    if (n >= NNODES) return;
    int lane = tid & 63;
    int head = lane >> 4, sub = lane & 15;
    int e0 = offs[n], e1 = offs[n + 1];
    float adh = ald[n * NH + head];

    float m = -1e30f;
    for (int k = e0 + sub; k < e1; k += 16)
        m = fmaxf(m, leaky(als[srcs[k] * NH + head] + adh));
    #pragma unroll
    for (int o = 1; o < 16; o <<= 1) m = fmaxf(m, __shfl_xor(m, o));
    float d = 0.f;
    for (int k = e0 + sub; k < e1; k += 16)
        d += __expf(leaky(als[srcs[k] * NH + head] + adh) - m);
    #pragma unroll
    for (int o = 1; o < 16; o <<= 1) d += __shfl_xor(d, o);
    float dinv = 1.f / d;
    for (int k = e0 + sub; k < e1; k += 16)
        alpha[k * NH + head] = __expf(leaky(als[srcs[k] * NH + head] + adh) - m) * dinv;
}

// ------ GAT aggregation + bias + LayerNorm + ELU (one wave per node) --------

__global__ __launch_bounds__(256) void k_gat_aggregate(
        const bf16* __restrict__ h, const float* __restrict__ alpha,
        const int* __restrict__ offs, const int* __restrict__ srcs,
        const float* __restrict__ bias, const float* __restrict__ gamma,
        const float* __restrict__ beta, bf16* __restrict__ out) {
    int tid = threadIdx.x;
    int n = blockIdx.x * 4 + (tid >> 6);
    if (n >= NNODES) return;
    int lane = tid & 63;
    int head = lane >> 4;
    int ch0 = lane * 8;
    int e0 = offs[n], e1 = offs[n + 1];

    float acc[8] = {};
    for (int base = e0; base < e1; base += 64) {
        int cnt = min(64, e1 - base);
        int sv = (base + lane < e1) ? srcs[base + lane] : 0;
        int k = 0;
        for (; k + 4 <= cnt; k += 4) {
            int s0 = __shfl(sv, k),     s1 = __shfl(sv, k + 1);
            int s2 = __shfl(sv, k + 2), s3 = __shfl(sv, k + 3);
            float p0 = alpha[(base + k)     * NH + head];
            float p1 = alpha[(base + k + 1) * NH + head];
            float p2 = alpha[(base + k + 2) * NH + head];
            float p3 = alpha[(base + k + 3) * NH + head];
            short8 h0 = *reinterpret_cast<const short8*>(&h[(size_t)s0 * D1 + ch0]);
            short8 h1 = *reinterpret_cast<const short8*>(&h[(size_t)s1 * D1 + ch0]);
            short8 h2 = *reinterpret_cast<const short8*>(&h[(size_t)s2 * D1 + ch0]);
            short8 h3 = *reinterpret_cast<const short8*>(&h[(size_t)s3 * D1 + ch0]);
            #pragma unroll
            for (int j = 0; j < 8; j++)
                acc[j] += p0 * bf2f(h0[j]) + p1 * bf2f(h1[j])
                        + p2 * bf2f(h2[j]) + p3 * bf2f(h3[j]);
        }
        for (; k < cnt; k++) {
            int s0 = __shfl(sv, k);
            float p0 = alpha[(base + k) * NH + head];
            short8 h0 = *reinterpret_cast<const short8*>(&h[(size_t)s0 * D1 + ch0]);
            #pragma unroll
            for (int j = 0; j < 8; j++) acc[j] += p0 * bf2f(h0[j]);
        }
    }

    // bias + LayerNorm(512) + ELU, wave-wide shuffle reduce
    float v[8];
    float ps = 0.f;
    #pragma unroll
    for (int j = 0; j < 8; j++) { v[j] = acc[j] + bias[ch0 + j]; ps += v[j]; }
    #pragma unroll
    for (int o = 1; o < 64; o <<= 1) ps += __shfl_xor(ps, o);
    float mu = ps * (1.f / 512.f);
    float qs = 0.f;
    #pragma unroll
    for (int j = 0; j < 8; j++) { float dvj = v[j] - mu; qs += dvj * dvj; }
    #pragma unroll
    for (int o = 1; o < 64; o <<= 1) qs += __shfl_xor(qs, o);
    float rstd = rsqrtf(qs * (1.f / 512.f) + LN_EPS);

    short8 ov;
    #pragma unroll
    for (int j = 0; j < 8; j++) {
        float y = (v[j] - mu) * rstd * gamma[ch0 + j] + beta[ch0 + j];
        float e = (y > 0.f) ? y : (__expf(y) - 1.f);
        ov[j] = f2bf(e);
    }
    *reinterpret_cast<short8*>(&out[(size_t)n * D1 + ch0]) = ov;
}

// ---------------- bf16 MFMA GEMM: C = A[MPAD,K] @ Bt[N,K]^T ----------------
// 128x128 tile, 4 waves (2x2 of 64x64), 16x16x32 bf16 MFMA, K-step 32.

#define EPI_BF       0   // C -> bf16
#define EPI_BRELU_BF 1   // relu(C + bias) -> bf16
#define EPI_CLS      2   // atomicAdd(out, relu(C+bias) @ Wc2 (+bc2))

template<int EPI>
__global__ __launch_bounds__(256) void gemm_bf16(
    const ushort* __restrict__ A, const ushort* __restrict__ Bt,
    const float* __restrict__ bias, bf16* __restrict__ Obf,
    float* __restrict__ Of32, const float* __restrict__ Wc2,
    int Mreal, int N, int K, const float* __restrict__ bc2) {
    __shared__ __align__(16) ushort As[128 * 32];
    __shared__ __align__(16) ushort Bs[128 * 32];
    int tid = threadIdx.x;
    int wave = tid >> 6, lane = tid & 63;
    int brow = blockIdx.y * 128;
    int bcol = blockIdx.x * 128;
    int wm = (wave >> 1) * 64, wn = (wave & 1) * 64;

    f32x4 acc[4][4] = {};

    int ldr = lane >> 2;          // 0..15 row within chunk
    int ldk = (lane & 3) * 8;     // k element offset within 32

    for (int k0 = 0; k0 < K; k0 += 32) {
        if (k0) __syncthreads();
        #pragma unroll
        for (int c2 = 0; c2 < 2; c2++) {
            int c = wave + c2 * 4;
            int row = c * 16 + ldr;
            GLDS16(A  + (size_t)(brow + row) * K + k0 + ldk, As + c * 512);
            GLDS16(Bt + (size_t)(bcol + row) * K + k0 + ldk, Bs + c * 512);
        }
        __syncthreads();

        short8 af[4], bfr[4];
        int lr = lane & 15, lk = (lane >> 4) * 8;
        #pragma unroll
        for (int f = 0; f < 4; f++) {
            af[f]  = *reinterpret_cast<const short8*>(&As[(wm + f * 16 + lr) * 32 + lk]);
            bfr[f] = *reinterpret_cast<const short8*>(&Bs[(wn + f * 16 + lr) * 32 + lk]);
        }
        #pragma unroll
        for (int fm = 0; fm < 4; fm++)
            #pragma unroll
            for (int fn = 0; fn < 4; fn++)
                acc[fm][fn] = __builtin_amdgcn_mfma_f32_16x16x32_bf16(
                    af[fm], bfr[fn], acc[fm][fn], 0, 0, 0);
    }

    if (EPI == EPI_CLS) {
        // classifier fused: out[row,c] += sum_col relu(v+bias)*Wc2[col,c]
        float w2[4][2], b4[4];
        #pragma unroll
        for (int fn = 0; fn < 4; fn++) {
            int col = bcol + wn + fn * 16 + (lane & 15);
            w2[fn][0] = Wc2[col * 2];
            w2[fn][1] = Wc2[col * 2 + 1];
            b4[fn] = bias[col];
        }
        #pragma unroll
        for (int fm = 0; fm < 4; fm++) {
            #pragma unroll
            for (int r = 0; r < 4; r++) {
                int row = brow + wm + fm * 16 + (lane >> 4) * 4 + r;
                float s0 = 0.f, s1 = 0.f;
                #pragma unroll
                for (int fn = 0; fn < 4; fn++) {
                    float v = acc[fm][fn][r] + b4[fn];
                    v = v > 0.f ? v : 0.f;
                    s0 += v * w2[fn][0];
                    s1 += v * w2[fn][1];
                }
                #pragma unroll
                for (int o = 1; o < 16; o <<= 1) {
                    s0 += __shfl_xor(s0, o);
                    s1 += __shfl_xor(s1, o);
                }
                if ((lane & 15) == 0 && row < Mreal) {
                    if (bcol == 0 && wn == 0) { s0 += bc2[0]; s1 += bc2[1]; }
                    atomicAdd(&Of32[row * 2],     s0);
                    atomicAdd(&Of32[row * 2 + 1], s1);
                }
            }
        }
        return;
    }

    #pragma unroll
    for (int fm = 0; fm < 4; fm++) {
        int row0 = brow + wm + fm * 16 + (lane >> 4) * 4;
        #pragma unroll
        for (int fn = 0; fn < 4; fn++) {
            int col = bcol + wn + fn * 16 + (lane & 15);
            #pragma unroll
            for (int r = 0; r < 4; r++) {
                int row = row0 + r;
                if (row >= Mreal) continue;
                size_t idx = (size_t)row * N + col;
                float v = acc[fm][fn][r];
                if (EPI == EPI_BF) {
                    Obf[idx] = __float2bfloat16(v);
                } else {
                    v += bias[col]; v = v > 0.f ? v : 0.f;
                    Obf[idx] = __float2bfloat16(v);
                }
            }
        }
    }
}

// ------- dual GEMM: O = A2@B2t + rs*(A1@B1t) + (bias2 + rs*bias1) -> bf16 ----
// h_comb = h1@Wr + br + rscale*(t@We2 + bE2)

__global__ __launch_bounds__(256) void gemm_dual(
    const ushort* __restrict__ A1, const ushort* __restrict__ B1t,   // t, We2t
    const ushort* __restrict__ A2, const ushort* __restrict__ B2t,   // h1, Wrt
    const float* __restrict__ bias1, const float* __restrict__ bias2,
    bf16* __restrict__ Obf, int Mreal, int N, int K,
    const float* __restrict__ rsc) {
    __shared__ __align__(16) ushort As[128 * 32];
    __shared__ __align__(16) ushort Bs[128 * 32];
    int tid = threadIdx.x;
    int wave = tid >> 6, lane = tid & 63;
    int brow = blockIdx.y * 128;
    int bcol = blockIdx.x * 128;
    int wm = (wave >> 1) * 64, wn = (wave & 1) * 64;
    float rs = *rsc;

    f32x4 acc[4][4] = {};

    int ldr = lane >> 2;
    int ldk = (lane & 3) * 8;
    int lr = lane & 15, lk = (lane >> 4) * 8;

    #pragma unroll
    for (int phase = 0; phase < 2; phase++) {
        const ushort* Ap = phase ? A2 : A1;
        const ushort* Bp = phase ? B2t : B1t;
        if (phase) {   // scale accumulated first product by rs
            __syncthreads();
            #pragma unroll
            for (int fm = 0; fm < 4; fm++)
                #pragma unroll
                for (int fn = 0; fn < 4; fn++)
                    #pragma unroll
                    for (int r = 0; r < 4; r++) acc[fm][fn][r] *= rs;
        }
        for (int k0 = 0; k0 < K; k0 += 32) {
            if (k0 || phase) __syncthreads();
            #pragma unroll
            for (int c2 = 0; c2 < 2; c2++) {
                int c = wave + c2 * 4;
                int row = c * 16 + ldr;
                GLDS16(Ap + (size_t)(brow + row) * K + k0 + ldk, As + c * 512);
                GLDS16(Bp + (size_t)(bcol + row) * K + k0 + ldk, Bs + c * 512);
            }
            __syncthreads();

            short8 af[4], bfr[4];
            #pragma unroll
            for (int f = 0; f < 4; f++) {
                af[f]  = *reinterpret_cast<const short8*>(&As[(wm + f * 16 + lr) * 32 + lk]);
                bfr[f] = *reinterpret_cast<const short8*>(&Bs[(wn + f * 16 + lr) * 32 + lk]);
            }
            #pragma unroll
            for (int fm = 0; fm < 4; fm++)
                #pragma unroll
                for (int fn = 0; fn < 4; fn++)
                    acc[fm][fn] = __builtin_amdgcn_mfma_f32_16x16x32_bf16(
                        af[fm], bfr[fn], acc[fm][fn], 0, 0, 0);
        }
    }

    #pragma unroll
    for (int fm = 0; fm < 4; fm++) {
        int row0 = brow + wm + fm * 16 + (lane >> 4) * 4;
        #pragma unroll
        for (int fn = 0; fn < 4; fn++) {
            int col = bcol + wn + fn * 16 + (lane & 15);
            float be = bias2[col] + rs * bias1[col];
            #pragma unroll
            for (int r = 0; r < 4; r++) {
                int row = row0 + r;
                if (row >= Mreal) continue;
                Obf[(size_t)row * N + col] = __float2bfloat16(acc[fm][fn][r] + be);
            }
        }
    }
}

// ---------------- launch ----------------

extern "C" void kernel_launch(void* const* d_in, const int* in_sizes, int n_in,
                              void* d_out, int out_size, void* d_ws, size_t ws_size,
                              hipStream_t stream) {
    const float* x   = (const float*)d_in[0];
    const int*   ei  = (const int*)d_in[1];
    const float* W1  = (const float*)d_in[2];
    const float* as1 = (const float*)d_in[3];
    const float* ad1 = (const float*)d_in[4];
    const float* b1  = (const float*)d_in[5];
    const float* g1  = (const float*)d_in[6];
    const float* bn1 = (const float*)d_in[7];
    const float* We1 = (const float*)d_in[8];
    const float* bE1 = (const float*)d_in[9];
    const float* We2 = (const float*)d_in[10];
    const float* bE2 = (const float*)d_in[11];
    const float* Wr  = (const float*)d_in[12];
    const float* br  = (const float*)d_in[13];
    const float* rsc = (const float*)d_in[14];
    const float* W2  = (const float*)d_in[15];
    const float* as2 = (const float*)d_in[16];
    const float* ad2 = (const float*)d_in[17];
    const float* b2  = (const float*)d_in[18];
    const float* g2  = (const float*)d_in[19];
    const float* bn2 = (const float*)d_in[20];
    const float* Wc1 = (const float*)d_in[21];
    const float* bc1 = (const float*)d_in[22];
    const float* Wc2 = (const float*)d_in[23];
    const float* bc2 = (const float*)d_in[24];
    float* out = (float*)d_out;

    char* ws = (char*)d_ws;
    size_t o = 0;
    auto alloc = [&](size_t bytes) { void* p = ws + o; o += (bytes + 255) & ~255ull; return p; };
    bf16* xb    = (bf16*)alloc((size_t)MPAD * 192 * 2);
    bf16* bufA  = (bf16*)alloc((size_t)MPAD * D1 * 2);   // h (per layer)
    bf16* bufB  = (bf16*)alloc((size_t)MPAD * D1 * 2);   // h1, h2
    bf16* bufC  = (bf16*)alloc((size_t)MPAD * D1 * 2);   // t (expansion)
    bf16* hcb   = (bf16*)alloc((size_t)MPAD * 256 * 2);  // h_comb bf16
    bf16* W1t   = (bf16*)alloc((size_t)512 * 192 * 2);
    bf16* We1t  = (bf16*)alloc((size_t)512 * 512 * 2);
    bf16* We2t  = (bf16*)alloc((size_t)256 * 512 * 2);
    bf16* Wrt   = (bf16*)alloc((size_t)256 * 512 * 2);
    bf16* W2t   = (bf16*)alloc((size_t)512 * 256 * 2);
    bf16* Wc1t  = (bf16*)alloc((size_t)512 * 512 * 2);
    float* als  = (float*)alloc((size_t)NNODES * NH * 4);
    float* ald  = (float*)alloc((size_t)NNODES * NH * 4);
    float* alpha= (float*)alloc((size_t)NTOT * NH * 4);
    int* counts = (int*)alloc((NNODES + 1) * 4);
    int* offs   = (int*)alloc((NNODES + 1) * 4);
    int* cursor = (int*)alloc((NNODES + 1) * 4);
    int* srcs   = (int*)alloc((size_t)NTOT * 4);

    // CSR by dst (shared by both GAT layers)
    hipMemsetAsync(counts, 0, NNODES * 4, stream);
    k_count<<<(NTOT + 255) / 256, 256, 0, stream>>>(ei, counts);
    k_scan<<<1, 1024, 0, stream>>>(counts, offs);
    hipMemcpyAsync(cursor, offs, (NNODES + 1) * 4, hipMemcpyDeviceToDevice, stream);
    k_fill<<<(NTOT + 255) / 256, 256, 0, stream>>>(ei, cursor, srcs);

    // weight conversion (transposed bf16)
    k_wt<<<(512 * 192 + 255) / 256, 256, 0, stream>>>(W1,  W1t,  182, 512, 192);
    k_wt<<<(512 * 512 + 255) / 256, 256, 0, stream>>>(We1, We1t, 512, 512, 512);
    k_wt<<<(256 * 512 + 255) / 256, 256, 0, stream>>>(We2, We2t, 512, 256, 512);
    k_wt<<<(256 * 512 + 255) / 256, 256, 0, stream>>>(Wr,  Wrt,  512, 256, 512);
    k_wt<<<(512 * 256 + 255) / 256, 256, 0, stream>>>(W2,  W2t,  256, 512, 256);
    k_wt<<<(512 * 512 + 255) / 256, 256, 0, stream>>>(Wc1, Wc1t, 512, 512, 512);
    k_xconv<<<(MPAD * 192 + 255) / 256, 256, 0, stream>>>(x, xb);

    dim3 blk(256);
    dim3 g512(4, MPAD / 128), g256(2, MPAD / 128);
    int nwb = (NNODES + 3) / 4;   // wave-per-node kernels: 4 waves/block

    // GAT layer 1
    gemm_bf16<EPI_BF><<<g512, blk, 0, stream>>>((const ushort*)xb, (const ushort*)W1t,
        nullptr, bufA, nullptr, nullptr, NNODES, 512, 192, nullptr);
    k_attn_logits<<<nwb, blk, 0, stream>>>(bufA, as1, ad1, als, ald);
    k_edge_alpha<<<nwb, blk, 0, stream>>>(als, ald, offs, srcs, alpha);
    k_gat_aggregate<<<nwb, blk, 0, stream>>>(bufA, alpha, offs, srcs, b1, g1, bn1, bufB);

    // expansion MLP + residual combine (fused)
    gemm_bf16<EPI_BRELU_BF><<<g512, blk, 0, stream>>>((const ushort*)bufB, (const ushort*)We1t,
        bE1, bufC, nullptr, nullptr, NNODES, 512, 512, nullptr);
    gemm_dual<<<g256, blk, 0, stream>>>((const ushort*)bufC, (const ushort*)We2t,
        (const ushort*)bufB, (const ushort*)Wrt, bE2, br, hcb, NNODES, 256, 512, rsc);

    // GAT layer 2
    gemm_bf16<EPI_BF><<<g512, blk, 0, stream>>>((const ushort*)hcb, (const ushort*)W2t,
        nullptr, bufA, nullptr, nullptr, NNODES, 512, 256, nullptr);
    k_attn_logits<<<nwb, blk, 0, stream>>>(bufA, as2, ad2, als, ald);
    k_edge_alpha<<<nwb, blk, 0, stream>>>(als, ald, offs, srcs, alpha);
    k_gat_aggregate<<<nwb, blk, 0, stream>>>(bufA, alpha, offs, srcs, b2, g2, bn2, bufB);

    // classifier fused into Wc1 GEMM epilogue
    hipMemsetAsync(out, 0, (size_t)out_size * 4, stream);
    gemm_bf16<EPI_CLS><<<g512, blk, 0, stream>>>((const ushort*)bufB, (const ushort*)Wc1t,
        bc1, nullptr, out, Wc2, NNODES, 512, 512, bc2);
}

// Round 6
// 560.975 us; speedup vs baseline: 5.4122x; 1.1537x over previous
//
#include <hip/hip_runtime.h>
#include <hip/hip_bf16.h>
#include <math.h>

#define NNODES 50000
#define NEDGES 500000
#define NTOT   (NEDGES + NNODES)   // 550000 edges incl. self-loops
#define MPAD   50048               // 391 * 128
#define D1     512
#define NH     4
#define LN_EPS 1e-5f
#define NEG_SLOPE 0.2f

#define SBLK 256
#define NSB  ((NNODES + SBLK - 1) / SBLK)   // 196

typedef __attribute__((ext_vector_type(8))) short short8;
typedef __attribute__((ext_vector_type(4))) float f32x4;
typedef __hip_bfloat16 bf16;

#define GLDS16(g, l) __builtin_amdgcn_global_load_lds( \
    (const __attribute__((address_space(1))) void*)(g), \
    (__attribute__((address_space(3))) void*)(l), 16, 0, 0)

__device__ __forceinline__ float bf2f(short u) {
    unsigned int x = ((unsigned int)(unsigned short)u) << 16;
    return __uint_as_float(x);
}
__device__ __forceinline__ short f2bf(float f) {   // RNE
    unsigned int x = __float_as_uint(f);
    unsigned int r = (x + 0x7fffu + ((x >> 16) & 1u)) >> 16;
    return (short)r;
}
__device__ __forceinline__ float leaky(float e) {
    return (e >= 0.f) ? e : NEG_SLOPE * e;
}

// ---------------- CSR build (counting sort by dst) ----------------

__global__ void k_count(const int* __restrict__ ei, int* __restrict__ counts) {
    int e = blockIdx.x * blockDim.x + threadIdx.x;
    if (e >= NTOT) return;
    int d = (e < NEDGES) ? ei[NEDGES + e] : (e - NEDGES);
    atomicAdd(&counts[d], 1);
}

// hierarchical exclusive scan: local scan + block sums
__global__ void k_scan1(const int* __restrict__ counts, int* __restrict__ offs,
                        int* __restrict__ bsums) {
    __shared__ int s[SBLK];
    int tid = threadIdx.x, b = blockIdx.x;
    int idx = b * SBLK + tid;
    int v = (idx < NNODES) ? counts[idx] : 0;
    s[tid] = v;
    __syncthreads();
    for (int d = 1; d < SBLK; d <<= 1) {
        int t = (tid >= d) ? s[tid - d] : 0;
        __syncthreads();
        s[tid] += t;
        __syncthreads();
    }
    if (idx < NNODES) offs[idx] = s[tid] - v;   // local exclusive
    if (tid == SBLK - 1) bsums[b] = s[tid];
}

__global__ void k_scan2(const int* __restrict__ bsums, int* __restrict__ bbase) {
    __shared__ int s[256];
    int tid = threadIdx.x;
    int v = (tid < NSB) ? bsums[tid] : 0;
    s[tid] = v;
    __syncthreads();
    for (int d = 1; d < 256; d <<= 1) {
        int t = (tid >= d) ? s[tid - d] : 0;
        __syncthreads();
        s[tid] += t;
        __syncthreads();
    }
    bbase[tid] = s[tid] - v;                     // exclusive
    if (tid == 255) bbase[256] = s[255];         // total
}

__global__ void k_scan3(int* __restrict__ offs, const int* __restrict__ bbase,
                        int* __restrict__ cursor) {
    int idx = blockIdx.x * 256 + threadIdx.x;
    if (idx < NNODES) {
        int v = offs[idx] + bbase[idx >> 8];
        offs[idx] = v;
        cursor[idx] = v;
    }
    if (idx == 0) offs[NNODES] = bbase[256];
}

__global__ void k_fill(const int* __restrict__ ei, int* __restrict__ cursor,
                       int* __restrict__ srcs) {
    int e = blockIdx.x * blockDim.x + threadIdx.x;
    if (e >= NTOT) return;
    int s, d;
    if (e < NEDGES) { s = ei[e]; d = ei[NEDGES + e]; }
    else            { s = d = e - NEDGES; }
    int pos = atomicAdd(&cursor[d], 1);
    srcs[pos] = s;
}

// ---------------- conversions ----------------

// all six weight matrices, transposed to [N][Kpad] bf16, one dispatch
__global__ void k_wt_all(const float* __restrict__ W1, const float* __restrict__ We1,
                         const float* __restrict__ We2, const float* __restrict__ Wr,
                         const float* __restrict__ W2, const float* __restrict__ Wc1,
                         bf16* __restrict__ W1t, bf16* __restrict__ We1t,
                         bf16* __restrict__ We2t, bf16* __restrict__ Wrt,
                         bf16* __restrict__ W2t, bf16* __restrict__ Wc1t) {
    int which = blockIdx.y;
    const float* W; bf16* Wt; int K, N, Kpad;
    switch (which) {
        case 0:  W = W1;  Wt = W1t;  K = 182; N = 512; Kpad = 192; break;
        case 1:  W = We1; Wt = We1t; K = 512; N = 512; Kpad = 512; break;
        case 2:  W = We2; Wt = We2t; K = 512; N = 256; Kpad = 512; break;
        case 3:  W = Wr;  Wt = Wrt;  K = 512; N = 256; Kpad = 512; break;
        case 4:  W = W2;  Wt = W2t;  K = 256; N = 512; Kpad = 256; break;
        default: W = Wc1; Wt = Wc1t; K = 512; N = 512; Kpad = 512; break;
    }
    int idx = blockIdx.x * 256 + threadIdx.x;
    if (idx >= N * Kpad) return;
    int n = idx / Kpad, k = idx % Kpad;
    float v = (k < K) ? W[(size_t)k * N + n] : 0.f;
    Wt[idx] = __float2bfloat16(v);
}

__global__ void k_xconv(const float* __restrict__ x, bf16* __restrict__ xb) {
    int idx = blockIdx.x * 256 + threadIdx.x;
    if (idx >= MPAD * 192) return;
    int r = idx / 192, k = idx % 192;
    float v = (r < NNODES && k < 182) ? x[(size_t)r * 182 + k] : 0.f;
    xb[idx] = __float2bfloat16(v);
}

// ---------------- attention logits: als/ald [N,H] (one wave per node) --------

__global__ __launch_bounds__(256) void k_attn_logits(
        const bf16* __restrict__ h, const float* __restrict__ a_s,
        const float* __restrict__ a_d, float* __restrict__ als,
        float* __restrict__ ald) {
    int tid = threadIdx.x;
    int n = blockIdx.x * 4 + (tid >> 6);
    if (n >= NNODES) return;
    int lane = tid & 63;
    int ch0 = lane * 8;
    short8 hv = *reinterpret_cast<const short8*>(&h[(size_t)n * D1 + ch0]);
    float s1 = 0.f, s2 = 0.f;
    #pragma unroll
    for (int j = 0; j < 8; j++) {
        float v = bf2f(hv[j]);
        s1 += v * a_s[ch0 + j];
        s2 += v * a_d[ch0 + j];
    }
    #pragma unroll
    for (int o = 1; o < 16; o <<= 1) {
        s1 += __shfl_xor(s1, o);
        s2 += __shfl_xor(s2, o);
    }
    if ((lane & 15) == 0) {
        int head = lane >> 4;
        als[n * NH + head] = s1;
        ald[n * NH + head] = s2;
    }
}

// -------- per-edge softmax alpha (one wave per node, edge-parallel) ---------

__global__ __launch_bounds__(256) void k_edge_alpha(
        const float* __restrict__ als, const float* __restrict__ ald,
        const int* __restrict__ offs, const int* __restrict__ srcs,
        float* __restrict__ alpha) {
    int tid = threadIdx.x;
    int n = blockIdx.x * 4 + (tid >> 6);
    if (n >= NNODES) return;
    int lane = tid & 63;
    int head = lane >> 4, sub = lane & 15;
    int e0 = offs[n], e1 = offs[n + 1];
    float adh = ald[n * NH + head];

    float m = -1e30f;
    for (int k = e0 + sub; k < e1; k += 16)
        m = fmaxf(m, leaky(als[srcs[k] * NH + head] + adh));
    #pragma unroll
    for (int o = 1; o < 16; o <<= 1) m = fmaxf(m, __shfl_xor(m, o));
    float d = 0.f;
    for (int k = e0 + sub; k < e1; k += 16)
        d += __expf(leaky(als[srcs[k] * NH + head] + adh) - m);
    #pragma unroll
    for (int o = 1; o < 16; o <<= 1) d += __shfl_xor(d, o);
    float dinv = 1.f / d;
    for (int k = e0 + sub; k < e1; k += 16)
        alpha[k * NH + head] = __expf(leaky(als[srcs[k] * NH + head] + adh) - m) * dinv;
}

// ------ GAT aggregation + bias + LayerNorm + ELU (one wave per node) --------

__global__ __launch_bounds__(256) void k_gat_aggregate(
        const bf16* __restrict__ h, const float* __restrict__ alpha,
        const int* __restrict__ offs, const int* __restrict__ srcs,
        const float* __restrict__ bias, const float* __restrict__ gamma,
        const float* __restrict__ beta, bf16* __restrict__ out) {
    int tid = threadIdx.x;
    int n = blockIdx.x * 4 + (tid >> 6);
    if (n >= NNODES) return;
    int lane = tid & 63;
    int head = lane >> 4;
    int ch0 = lane * 8;
    int e0 = offs[n], e1 = offs[n + 1];

    float acc[8] = {};
    for (int base = e0; base < e1; base += 64) {
        int cnt = min(64, e1 - base);
        int sv = (base + lane < e1) ? srcs[base + lane] : 0;
        int k = 0;
        for (; k + 4 <= cnt; k += 4) {
            int s0 = __shfl(sv, k),     s1 = __shfl(sv, k + 1);
            int s2 = __shfl(sv, k + 2), s3 = __shfl(sv, k + 3);
            float p0 = alpha[(base + k)     * NH + head];
            float p1 = alpha[(base + k + 1) * NH + head];
            float p2 = alpha[(base + k + 2) * NH + head];
            float p3 = alpha[(base + k + 3) * NH + head];
            short8 h0 = *reinterpret_cast<const short8*>(&h[(size_t)s0 * D1 + ch0]);
            short8 h1 = *reinterpret_cast<const short8*>(&h[(size_t)s1 * D1 + ch0]);
            short8 h2 = *reinterpret_cast<const short8*>(&h[(size_t)s2 * D1 + ch0]);
            short8 h3 = *reinterpret_cast<const short8*>(&h[(size_t)s3 * D1 + ch0]);
            #pragma unroll
            for (int j = 0; j < 8; j++)
                acc[j] += p0 * bf2f(h0[j]) + p1 * bf2f(h1[j])
                        + p2 * bf2f(h2[j]) + p3 * bf2f(h3[j]);
        }
        for (; k < cnt; k++) {
            int s0 = __shfl(sv, k);
            float p0 = alpha[(base + k) * NH + head];
            short8 h0 = *reinterpret_cast<const short8*>(&h[(size_t)s0 * D1 + ch0]);
            #pragma unroll
            for (int j = 0; j < 8; j++) acc[j] += p0 * bf2f(h0[j]);
        }
    }

    // bias + LayerNorm(512) + ELU, wave-wide shuffle reduce
    float v[8];
    float ps = 0.f;
    #pragma unroll
    for (int j = 0; j < 8; j++) { v[j] = acc[j] + bias[ch0 + j]; ps += v[j]; }
    #pragma unroll
    for (int o = 1; o < 64; o <<= 1) ps += __shfl_xor(ps, o);
    float mu = ps * (1.f / 512.f);
    float qs = 0.f;
    #pragma unroll
    for (int j = 0; j < 8; j++) { float dvj = v[j] - mu; qs += dvj * dvj; }
    #pragma unroll
    for (int o = 1; o < 64; o <<= 1) qs += __shfl_xor(qs, o);
    float rstd = rsqrtf(qs * (1.f / 512.f) + LN_EPS);

    short8 ov;
    #pragma unroll
    for (int j = 0; j < 8; j++) {
        float y = (v[j] - mu) * rstd * gamma[ch0 + j] + beta[ch0 + j];
        float e = (y > 0.f) ? y : (__expf(y) - 1.f);
        ov[j] = f2bf(e);
    }
    *reinterpret_cast<short8*>(&out[(size_t)n * D1 + ch0]) = ov;
}

// ---------------- bf16 MFMA GEMM: C = A[MPAD,K] @ Bt[N,K]^T ----------------
// 128x128 tile, 4 waves (2x2 of 64x64), 16x16x32 bf16 MFMA, K-step 32.

#define EPI_BF       0   // C -> bf16
#define EPI_BRELU_BF 1   // relu(C + bias) -> bf16
#define EPI_CLS      2   // atomicAdd(out, relu(C+bias) @ Wc2 (+bc2))

template<int EPI>
__global__ __launch_bounds__(256) void gemm_bf16(
    const ushort* __restrict__ A, const ushort* __restrict__ Bt,
    const float* __restrict__ bias, bf16* __restrict__ Obf,
    float* __restrict__ Of32, const float* __restrict__ Wc2,
    int Mreal, int N, int K, const float* __restrict__ bc2) {
    __shared__ __align__(16) ushort As[128 * 32];
    __shared__ __align__(16) ushort Bs[128 * 32];
    int tid = threadIdx.x;
    int wave = tid >> 6, lane = tid & 63;
    int brow = blockIdx.y * 128;
    int bcol = blockIdx.x * 128;
    int wm = (wave >> 1) * 64, wn = (wave & 1) * 64;

    f32x4 acc[4][4] = {};

    int ldr = lane >> 2;          // 0..15 row within chunk
    int ldk = (lane & 3) * 8;     // k element offset within 32

    for (int k0 = 0; k0 < K; k0 += 32) {
        if (k0) __syncthreads();
        #pragma unroll
        for (int c2 = 0; c2 < 2; c2++) {
            int c = wave + c2 * 4;
            int row = c * 16 + ldr;
            GLDS16(A  + (size_t)(brow + row) * K + k0 + ldk, As + c * 512);
            GLDS16(Bt + (size_t)(bcol + row) * K + k0 + ldk, Bs + c * 512);
        }
        __syncthreads();

        short8 af[4], bfr[4];
        int lr = lane & 15, lk = (lane >> 4) * 8;
        #pragma unroll
        for (int f = 0; f < 4; f++) {
            af[f]  = *reinterpret_cast<const short8*>(&As[(wm + f * 16 + lr) * 32 + lk]);
            bfr[f] = *reinterpret_cast<const short8*>(&Bs[(wn + f * 16 + lr) * 32 + lk]);
        }
        #pragma unroll
        for (int fm = 0; fm < 4; fm++)
            #pragma unroll
            for (int fn = 0; fn < 4; fn++)
                acc[fm][fn] = __builtin_amdgcn_mfma_f32_16x16x32_bf16(
                    af[fm], bfr[fn], acc[fm][fn], 0, 0, 0);
    }

    if (EPI == EPI_CLS) {
        float w2[4][2], b4[4];
        #pragma unroll
        for (int fn = 0; fn < 4; fn++) {
            int col = bcol + wn + fn * 16 + (lane & 15);
            w2[fn][0] = Wc2[col * 2];
            w2[fn][1] = Wc2[col * 2 + 1];
            b4[fn] = bias[col];
        }
        #pragma unroll
        for (int fm = 0; fm < 4; fm++) {
            #pragma unroll
            for (int r = 0; r < 4; r++) {
                int row = brow + wm + fm * 16 + (lane >> 4) * 4 + r;
                float s0 = 0.f, s1 = 0.f;
                #pragma unroll
                for (int fn = 0; fn < 4; fn++) {
                    float v = acc[fm][fn][r] + b4[fn];
                    v = v > 0.f ? v : 0.f;
                    s0 += v * w2[fn][0];
                    s1 += v * w2[fn][1];
                }
                #pragma unroll
                for (int o = 1; o < 16; o <<= 1) {
                    s0 += __shfl_xor(s0, o);
                    s1 += __shfl_xor(s1, o);
                }
                if ((lane & 15) == 0 && row < Mreal) {
                    if (bcol == 0 && wn == 0) { s0 += bc2[0]; s1 += bc2[1]; }
                    atomicAdd(&Of32[row * 2],     s0);
                    atomicAdd(&Of32[row * 2 + 1], s1);
                }
            }
        }
        return;
    }

    #pragma unroll
    for (int fm = 0; fm < 4; fm++) {
        int row0 = brow + wm + fm * 16 + (lane >> 4) * 4;
        #pragma unroll
        for (int fn = 0; fn < 4; fn++) {
            int col = bcol + wn + fn * 16 + (lane & 15);
            #pragma unroll
            for (int r = 0; r < 4; r++) {
                int row = row0 + r;
                if (row >= Mreal) continue;
                size_t idx = (size_t)row * N + col;
                float v = acc[fm][fn][r];
                if (EPI == EPI_BF) {
                    Obf[idx] = __float2bfloat16(v);
                } else {
                    v += bias[col]; v = v > 0.f ? v : 0.f;
                    Obf[idx] = __float2bfloat16(v);
                }
            }
        }
    }
}

// ------- dual GEMM: O = A2@B2t + rs*(A1@B1t) + (bias2 + rs*bias1) -> bf16 ----

__global__ __launch_bounds__(256) void gemm_dual(
    const ushort* __restrict__ A1, const ushort* __restrict__ B1t,   // t, We2t
    const ushort* __restrict__ A2, const ushort* __restrict__ B2t,   // h1, Wrt
    const float* __restrict__ bias1, const float* __restrict__ bias2,
    bf16* __restrict__ Obf, int Mreal, int N, int K,
    const float* __restrict__ rsc) {
    __shared__ __align__(16) ushort As[128 * 32];
    __shared__ __align__(16) ushort Bs[128 * 32];
    int tid = threadIdx.x;
    int wave = tid >> 6, lane = tid & 63;
    int brow = blockIdx.y * 128;
    int bcol = blockIdx.x * 128;
    int wm = (wave >> 1) * 64, wn = (wave & 1) * 64;
    float rs = *rsc;

    f32x4 acc[4][4] = {};

    int ldr = lane >> 2;
    int ldk = (lane & 3) * 8;
    int lr = lane & 15, lk = (lane >> 4) * 8;

    #pragma unroll
    for (int phase = 0; phase < 2; phase++) {
        const ushort* Ap = phase ? A2 : A1;
        const ushort* Bp = phase ? B2t : B1t;
        if (phase) {
            __syncthreads();
            #pragma unroll
            for (int fm = 0; fm < 4; fm++)
                #pragma unroll
                for (int fn = 0; fn < 4; fn++)
                    #pragma unroll
                    for (int r = 0; r < 4; r++) acc[fm][fn][r] *= rs;
        }
        for (int k0 = 0; k0 < K; k0 += 32) {
            if (k0 || phase) __syncthreads();
            #pragma unroll
            for (int c2 = 0; c2 < 2; c2++) {
                int c = wave + c2 * 4;
                int row = c * 16 + ldr;
                GLDS16(Ap + (size_t)(brow + row) * K + k0 + ldk, As + c * 512);
                GLDS16(Bp + (size_t)(bcol + row) * K + k0 + ldk, Bs + c * 512);
            }
            __syncthreads();

            short8 af[4], bfr[4];
            #pragma unroll
            for (int f = 0; f < 4; f++) {
                af[f]  = *reinterpret_cast<const short8*>(&As[(wm + f * 16 + lr) * 32 + lk]);
                bfr[f] = *reinterpret_cast<const short8*>(&Bs[(wn + f * 16 + lr) * 32 + lk]);
            }
            #pragma unroll
            for (int fm = 0; fm < 4; fm++)
                #pragma unroll
                for (int fn = 0; fn < 4; fn++)
                    acc[fm][fn] = __builtin_amdgcn_mfma_f32_16x16x32_bf16(
                        af[fm], bfr[fn], acc[fm][fn], 0, 0, 0);
        }
    }

    #pragma unroll
    for (int fm = 0; fm < 4; fm++) {
        int row0 = brow + wm + fm * 16 + (lane >> 4) * 4;
        #pragma unroll
        for (int fn = 0; fn < 4; fn++) {
            int col = bcol + wn + fn * 16 + (lane & 15);
            float be = bias2[col] + rs * bias1[col];
            #pragma unroll
            for (int r = 0; r < 4; r++) {
                int row = row0 + r;
                if (row >= Mreal) continue;
                Obf[(size_t)row * N + col] = __float2bfloat16(acc[fm][fn][r] + be);
            }
        }
    }
}

// ---------------- launch ----------------

extern "C" void kernel_launch(void* const* d_in, const int* in_sizes, int n_in,
                              void* d_out, int out_size, void* d_ws, size_t ws_size,
                              hipStream_t stream) {
    const float* x   = (const float*)d_in[0];
    const int*   ei  = (const int*)d_in[1];
    const float* W1  = (const float*)d_in[2];
    const float* as1 = (const float*)d_in[3];
    const float* ad1 = (const float*)d_in[4];
    const float* b1  = (const float*)d_in[5];
    const float* g1  = (const float*)d_in[6];
    const float* bn1 = (const float*)d_in[7];
    const float* We1 = (const float*)d_in[8];
    const float* bE1 = (const float*)d_in[9];
    const float* We2 = (const float*)d_in[10];
    const float* bE2 = (const float*)d_in[11];
    const float* Wr  = (const float*)d_in[12];
    const float* br  = (const float*)d_in[13];
    const float* rsc = (const float*)d_in[14];
    const float* W2  = (const float*)d_in[15];
    const float* as2 = (const float*)d_in[16];
    const float* ad2 = (const float*)d_in[17];
    const float* b2  = (const float*)d_in[18];
    const float* g2  = (const float*)d_in[19];
    const float* bn2 = (const float*)d_in[20];
    const float* Wc1 = (const float*)d_in[21];
    const float* bc1 = (const float*)d_in[22];
    const float* Wc2 = (const float*)d_in[23];
    const float* bc2 = (const float*)d_in[24];
    float* out = (float*)d_out;

    char* ws = (char*)d_ws;
    size_t o = 0;
    auto alloc = [&](size_t bytes) { void* p = ws + o; o += (bytes + 255) & ~255ull; return p; };
    bf16* xb    = (bf16*)alloc((size_t)MPAD * 192 * 2);
    bf16* bufA  = (bf16*)alloc((size_t)MPAD * D1 * 2);   // h (per layer)
    bf16* bufB  = (bf16*)alloc((size_t)MPAD * D1 * 2);   // h1, h2
    bf16* bufC  = (bf16*)alloc((size_t)MPAD * D1 * 2);   // t (expansion)
    bf16* hcb   = (bf16*)alloc((size_t)MPAD * 256 * 2);  // h_comb bf16
    bf16* W1t   = (bf16*)alloc((size_t)512 * 192 * 2);
    bf16* We1t  = (bf16*)alloc((size_t)512 * 512 * 2);
    bf16* We2t  = (bf16*)alloc((size_t)256 * 512 * 2);
    bf16* Wrt   = (bf16*)alloc((size_t)256 * 512 * 2);
    bf16* W2t   = (bf16*)alloc((size_t)512 * 256 * 2);
    bf16* Wc1t  = (bf16*)alloc((size_t)512 * 512 * 2);
    float* als  = (float*)alloc((size_t)NNODES * NH * 4);
    float* ald  = (float*)alloc((size_t)NNODES * NH * 4);
    float* alpha= (float*)alloc((size_t)NTOT * NH * 4);
    int* counts = (int*)alloc((NNODES + 1) * 4);
    int* offs   = (int*)alloc((NNODES + 1) * 4);
    int* cursor = (int*)alloc((NNODES + 1) * 4);
    int* srcs   = (int*)alloc((size_t)NTOT * 4);
    int* bsums  = (int*)alloc((NSB + 1) * 4);
    int* bbase  = (int*)alloc(257 * 4);

    // CSR by dst (shared by both GAT layers)
    hipMemsetAsync(counts, 0, NNODES * 4, stream);
    k_count<<<(NTOT + 255) / 256, 256, 0, stream>>>(ei, counts);
    k_scan1<<<NSB, SBLK, 0, stream>>>(counts, offs, bsums);
    k_scan2<<<1, 256, 0, stream>>>(bsums, bbase);
    k_scan3<<<(NNODES + 255) / 256, 256, 0, stream>>>(offs, bbase, cursor);
    k_fill<<<(NTOT + 255) / 256, 256, 0, stream>>>(ei, cursor, srcs);

    // weight conversion (transposed bf16), one dispatch
    k_wt_all<<<dim3(1024, 6), 256, 0, stream>>>(W1, We1, We2, Wr, W2, Wc1,
                                                W1t, We1t, We2t, Wrt, W2t, Wc1t);
    k_xconv<<<(MPAD * 192 + 255) / 256, 256, 0, stream>>>(x, xb);

    dim3 blk(256);
    dim3 g512(4, MPAD / 128), g256(2, MPAD / 128);
    int nwb = (NNODES + 3) / 4;   // wave-per-node kernels: 4 waves/block

    // GAT layer 1
    gemm_bf16<EPI_BF><<<g512, blk, 0, stream>>>((const ushort*)xb, (const ushort*)W1t,
        nullptr, bufA, nullptr, nullptr, NNODES, 512, 192, nullptr);
    k_attn_logits<<<nwb, blk, 0, stream>>>(bufA, as1, ad1, als, ald);
    k_edge_alpha<<<nwb, blk, 0, stream>>>(als, ald, offs, srcs, alpha);
    k_gat_aggregate<<<nwb, blk, 0, stream>>>(bufA, alpha, offs, srcs, b1, g1, bn1, bufB);

    // expansion MLP + residual combine (fused)
    gemm_bf16<EPI_BRELU_BF><<<g512, blk, 0, stream>>>((const ushort*)bufB, (const ushort*)We1t,
        bE1, bufC, nullptr, nullptr, NNODES, 512, 512, nullptr);
    gemm_dual<<<g256, blk, 0, stream>>>((const ushort*)bufC, (const ushort*)We2t,
        (const ushort*)bufB, (const ushort*)Wrt, bE2, br, hcb, NNODES, 256, 512, rsc);

    // GAT layer 2
    gemm_bf16<EPI_BF><<<g512, blk, 0, stream>>>((const ushort*)hcb, (const ushort*)W2t,
        nullptr, bufA, nullptr, nullptr, NNODES, 512, 256, nullptr);
    k_attn_logits<<<nwb, blk, 0, stream>>>(bufA, as2, ad2, als, ald);
    k_edge_alpha<<<nwb, blk, 0, stream>>>(als, ald, offs, srcs, alpha);
    k_gat_aggregate<<<nwb, blk, 0, stream>>>(bufA, alpha, offs, srcs, b2, g2, bn2, bufB);

    // classifier fused into Wc1 GEMM epilogue
    hipMemsetAsync(out, 0, (size_t)out_size * 4, stream);
    gemm_bf16<EPI_CLS><<<g512, blk, 0, stream>>>((const ushort*)bufB, (const ushort*)Wc1t,
        bc1, nullptr, out, Wc2, NNODES, 512, 512, bc2);
}